// Round 1
// baseline (1547.241 us; speedup 1.0000x reference)
//
#include <hip/hip_runtime.h>
#include <hip/hip_bf16.h>

#define N_PTS 8192
#define NBATCH 4

using u16 = unsigned short;
typedef short bf16x8 __attribute__((ext_vector_type(8)));
typedef float f32x4 __attribute__((ext_vector_type(4)));
typedef u16   u16x8 __attribute__((ext_vector_type(8)));

__device__ __forceinline__ u16 f2b(float f){
  unsigned u = __float_as_uint(f);
  unsigned r = (u + 0x7fffu + ((u >> 16) & 1u)) >> 16;  // RNE
  return (u16)r;
}
__device__ __forceinline__ float b2f(u16 v){
  return __uint_as_float(((unsigned)v) << 16);
}

// ---------------------------------------------------------------------------
// Generic bf16-MFMA GEMM:  C[M x NC] = W[M x KD] * X[KD x NC] (+bias), batched
// over blockIdx.z. 128x128 tile, BK=64, 4 waves (2x2), 16x16x32 bf16 MFMA.
// LDS layouts sW[m][k], sX[n][k] (k contiguous) with XOR swizzle ((row&7)<<4).
// MODE 0: write bf16 out (row-split across outA/outB for stacked Wk/Wv)
// MODE 1: write bf16 out + atomically accumulate per-row sum / sumsq (BN stats)
// MODE 2: X is bf16 with per-k affine+relu transform (BN apply); epilogue
//         out = relu(acc + bias + resid) written fp32.
// ---------------------------------------------------------------------------
template<int MODE, int KD>
__global__ __launch_bounds__(256) void gemm_k(
    const float* __restrict__ WA, const float* __restrict__ WB,
    const float* __restrict__ bA, const float* __restrict__ bB,
    int splitRow,
    const void* __restrict__ Xv, long xBatch, int NC,
    u16* __restrict__ outA, long outABatch,
    u16* __restrict__ outB, long outBBatch,
    float* __restrict__ statSum, float* __restrict__ statSq,
    const float* __restrict__ xscale, const float* __restrict__ xshift,
    const float* __restrict__ resid, long rBatch,
    float* __restrict__ outF, long outFBatch)
{
  __shared__ __align__(16) char sW[16384];   // [128 m][64 k] bf16, swizzled
  __shared__ __align__(16) char sX[16384];   // [128 n][64 k] bf16, swizzled

  const int t    = threadIdx.x;
  const int lane = t & 63;
  const int wid  = t >> 6;
  const int wm   = wid >> 1, wn = wid & 1;
  const int b    = blockIdx.z;
  const int n0   = blockIdx.x * 128;
  const int m0   = blockIdx.y * 128;

  const float* Wp; const float* bp; int mrel; u16* outp = nullptr;
  if (m0 < splitRow){ Wp = WA; bp = bA; mrel = m0;
                      if (MODE <= 1) outp = outA + (long)b * outABatch; }
  else              { Wp = WB; bp = bB; mrel = m0 - splitRow;
                      if (MODE <= 1) outp = outB + (long)b * outBBatch; }

  f32x4 acc[4][4];
  #pragma unroll
  for (int i = 0; i < 4; ++i)
    #pragma unroll
    for (int j = 0; j < 4; ++j) acc[i][j] = (f32x4){0.f, 0.f, 0.f, 0.f};

  const int m_off = t >> 1, Whalf = t & 1;   // W staging map
  const int k_off = t >> 2, cq    = t & 3;   // X staging map

  for (int ks = 0; ks < KD / 64; ++ks){
    const int k0 = ks * 64;

    // ---- stage W chunk [128 x 64] fp32 -> bf16 (k-contiguous, swizzled)
    {
      const float4* src = reinterpret_cast<const float4*>(
          Wp + (long)(mrel + m_off) * KD + k0 + Whalf * 32);
      #pragma unroll
      for (int i = 0; i < 4; ++i){
        float4 fa = src[2*i], fb = src[2*i+1];
        u16x8 p;
        p[0]=f2b(fa.x); p[1]=f2b(fa.y); p[2]=f2b(fa.z); p[3]=f2b(fa.w);
        p[4]=f2b(fb.x); p[5]=f2b(fb.y); p[6]=f2b(fb.z); p[7]=f2b(fb.w);
        int bo = (m_off*128 + Whalf*64 + i*16) ^ ((m_off & 7) << 4);
        *reinterpret_cast<u16x8*>(sW + bo) = p;
      }
    }
    // ---- stage X chunk [64 k x 128 n] -> sX[n][k] (transpose-on-store)
    if (MODE != 2){
      const float* Xf = (const float*)Xv + (long)b * xBatch;
      const float4* src = reinterpret_cast<const float4*>(
          Xf + (long)(k0 + k_off) * NC + n0 + cq * 32);
      #pragma unroll
      for (int i = 0; i < 8; ++i){
        float4 f = src[i];
        int n = cq*32 + i*4;
        *(u16*)(sX + ((((n+0)*128) + k_off*2) ^ (((n+0)&7)<<4))) = f2b(f.x);
        *(u16*)(sX + ((((n+1)*128) + k_off*2) ^ (((n+1)&7)<<4))) = f2b(f.y);
        *(u16*)(sX + ((((n+2)*128) + k_off*2) ^ (((n+2)&7)<<4))) = f2b(f.z);
        *(u16*)(sX + ((((n+3)*128) + k_off*2) ^ (((n+3)&7)<<4))) = f2b(f.w);
      }
    } else {
      const u16* Xh = (const u16*)Xv + (long)b * xBatch;
      const u16x8* src = reinterpret_cast<const u16x8*>(
          Xh + (long)(k0 + k_off) * NC + n0 + cq * 32);
      const float sc = xscale[k0 + k_off], sh = xshift[k0 + k_off];
      #pragma unroll
      for (int i = 0; i < 4; ++i){
        u16x8 uv = src[i];
        #pragma unroll
        for (int j = 0; j < 8; ++j){
          float x = fmaxf(b2f(uv[j]) * sc + sh, 0.f);   // BN + ReLU on load
          int n = cq*32 + i*8 + j;
          *(u16*)(sX + ((n*128 + k_off*2) ^ ((n&7)<<4))) = f2b(x);
        }
      }
    }
    __syncthreads();

    // ---- MFMA: 2 k-halves x 4x4 fragments
    #pragma unroll
    for (int kk = 0; kk < 2; ++kk){
      bf16x8 af[4], bfr[4];
      #pragma unroll
      for (int mi = 0; mi < 4; ++mi){
        int m  = wm*64 + mi*16 + (lane & 15);
        int bo = (m*128 + kk*64 + (lane>>4)*16) ^ ((m & 7) << 4);
        af[mi] = *reinterpret_cast<const bf16x8*>(sW + bo);
      }
      #pragma unroll
      for (int ni = 0; ni < 4; ++ni){
        int n  = wn*64 + ni*16 + (lane & 15);
        int bo = (n*128 + kk*64 + (lane>>4)*16) ^ ((n & 7) << 4);
        bfr[ni] = *reinterpret_cast<const bf16x8*>(sX + bo);
      }
      #pragma unroll
      for (int mi = 0; mi < 4; ++mi)
        #pragma unroll
        for (int ni = 0; ni < 4; ++ni)
          acc[mi][ni] = __builtin_amdgcn_mfma_f32_16x16x32_bf16(
              af[mi], bfr[ni], acc[mi][ni], 0, 0, 0);
    }
    __syncthreads();
  }

  // ---- epilogue (C/D layout: col = lane&15, row = (lane>>4)*4 + j)
  #pragma unroll
  for (int mi = 0; mi < 4; ++mi){
    #pragma unroll
    for (int j = 0; j < 4; ++j){
      const int rl = mrel + wm*64 + mi*16 + (lane>>4)*4 + j;
      const float bv = bp[rl];
      float s = 0.f, sq = 0.f;
      #pragma unroll
      for (int ni = 0; ni < 4; ++ni){
        const int cl = n0 + wn*64 + ni*16 + (lane & 15);
        float v = acc[mi][ni][j] + bv;
        if (MODE <= 1) outp[(long)rl * NC + cl] = f2b(v);
        if (MODE == 1){ s += v; sq += v * v; }
        if (MODE == 2){
          float r = resid[(long)b * rBatch + (long)rl * NC + cl];
          outF[(long)b * outFBatch + (long)rl * NC + cl] = fmaxf(v + r, 0.f);
        }
      }
      if (MODE == 1){
        #pragma unroll
        for (int off = 1; off < 16; off <<= 1){
          s  += __shfl_xor(s,  off);
          sq += __shfl_xor(sq, off);
        }
        if ((lane & 15) == 0){
          atomicAdd(&statSum[rl], s);
          atomicAdd(&statSq[rl],  sq);
        }
      }
    }
  }
}

// ---------------------------------------------------------------------------
// Per-point attention: 4 points/block, 4 heads. q,k,v bf16 staged in LDS;
// logits = q^T k * d^-0.5, softmax over 16, agg = v @ soft^T + queries resid.
// ---------------------------------------------------------------------------
__global__ __launch_bounds__(256) void attn_k(
    const u16* __restrict__ qg, const u16* __restrict__ kg,
    const u16* __restrict__ vg, const float* __restrict__ queries,
    float* __restrict__ aggF)
{
  __shared__ __align__(16) u16 sK[4][256][16];
  __shared__             u16 sV[4][256][18];     // pad 18 -> conflict-free PV
  __shared__ __align__(16) u16 sQ[4][256][4];
  __shared__ __align__(16) float sS[4][4][16][4]; // soft[p][h][kk][r]

  const int t  = threadIdx.x;
  const int b  = blockIdx.y;
  const int n0 = blockIdx.x * 4;
  const int N  = N_PTS;

  // ---- stage K, V (coalesced within 32B rows; lines shared across 4 points)
  #pragma unroll
  for (int it = 0; it < 8; ++it){
    int item = it*256 + t;
    int p = item >> 9, rem = item & 511;
    int c = rem >> 1, half = rem & 1;
    long gb = ((long)(b*256 + c) * N + (n0 + p)) * 16 + half*8;
    uint4 kw = *reinterpret_cast<const uint4*>(kg + gb);
    *reinterpret_cast<uint4*>((char*)(&sK[0][0][0]) + (p*256 + c)*32 + half*16) = kw;
    uint4 vw = *reinterpret_cast<const uint4*>(vg + gb);
    unsigned* vp = reinterpret_cast<unsigned*>(&sV[p][c][half*8]);
    vp[0] = vw.x; vp[1] = vw.y; vp[2] = vw.z; vp[3] = vw.w;
  }
  // ---- stage Q
  #pragma unroll
  for (int it = 0; it < 4; ++it){
    int item = it*256 + t;
    int p = item >> 8, c = item & 255;
    long gb = ((long)(b*256 + c) * N + (n0 + p)) * 4;
    *reinterpret_cast<uint2*>(&sQ[p][c][0]) =
        *reinterpret_cast<const uint2*>(qg + gb);
  }
  __syncthreads();

  // ---- phase A: logits + softmax. thread = (p, h, kk); shfl over 16 kk-lanes
  {
    const int p = t >> 6, h = (t >> 4) & 3, kk = t & 15;
    float l0=0.f, l1=0.f, l2=0.f, l3=0.f;
    #pragma unroll 4
    for (int d = 0; d < 64; ++d){
      int c = h*64 + d;
      float kv = b2f(sK[p][c][kk]);
      uint2 q2 = *reinterpret_cast<const uint2*>(&sQ[p][c][0]);
      l0 = fmaf(kv, b2f((u16)(q2.x & 0xffff)), l0);
      l1 = fmaf(kv, b2f((u16)(q2.x >> 16)),    l1);
      l2 = fmaf(kv, b2f((u16)(q2.y & 0xffff)), l2);
      l3 = fmaf(kv, b2f((u16)(q2.y >> 16)),    l3);
    }
    float lv[4] = {l0, l1, l2, l3};
    #pragma unroll
    for (int r = 0; r < 4; ++r){
      float x = lv[r] * 0.125f;                 // d^-0.5 = 1/8
      float m = x;
      #pragma unroll
      for (int off = 1; off < 16; off <<= 1) m = fmaxf(m, __shfl_xor(m, off));
      float e = __expf(x - m);
      float ssum = e;
      #pragma unroll
      for (int off = 1; off < 16; off <<= 1) ssum += __shfl_xor(ssum, off);
      sS[p][h][kk][r] = e / ssum;
    }
  }
  __syncthreads();

  // ---- phase B: agg = v @ soft^T (+ queries residual). thread = (p, c-lane)
  {
    const int p = t >> 6, cl = t & 63;
    #pragma unroll
    for (int hh = 0; hh < 4; ++hh){
      int c = hh*64 + cl;
      float a0=0.f, a1=0.f, a2=0.f, a3=0.f;
      #pragma unroll
      for (int kk = 0; kk < 16; kk += 2){
        unsigned vv = *reinterpret_cast<const unsigned*>(&sV[p][c][kk]);
        float v0 = b2f((u16)(vv & 0xffff));
        float v1 = b2f((u16)(vv >> 16));
        float4 s0 = *reinterpret_cast<const float4*>(&sS[p][hh][kk][0]);
        float4 s1 = *reinterpret_cast<const float4*>(&sS[p][hh][kk+1][0]);
        a0 += v0*s0.x + v1*s1.x;
        a1 += v0*s0.y + v1*s1.y;
        a2 += v0*s0.z + v1*s1.z;
        a3 += v0*s0.w + v1*s1.w;
      }
      long base = ((long)(b*256 + c) * N + (n0 + p)) * 4;
      float4 qr = *reinterpret_cast<const float4*>(&queries[base]);
      float4 o; o.x = a0+qr.x; o.y = a1+qr.y; o.z = a2+qr.z; o.w = a3+qr.w;
      *reinterpret_cast<float4*>(&aggF[base]) = o;
    }
  }
}

__global__ void zero_k(float* p){ p[blockIdx.x*256 + threadIdx.x] = 0.f; }

__global__ void finalize_k(const float* __restrict__ st,
                           const float* __restrict__ gamma,
                           const float* __restrict__ beta,
                           float* __restrict__ out)   // out: scale[512],shift[512]
{
  int o = blockIdx.x*256 + threadIdx.x;               // 0..511
  const float inv = 1.f / 131072.f;                   // B*N*R
  float mean = st[o] * inv;
  float var  = st[512 + o] * inv - mean*mean;
  float sc   = gamma[o] * rsqrtf(var + 1e-5f);
  out[o]       = sc;
  out[512 + o] = beta[o] - mean * sc;
}

// ---------------------------------------------------------------------------
extern "C" void kernel_launch(void* const* d_in, const int* in_sizes, int n_in,
                              void* d_out, int out_size, void* d_ws, size_t ws_size,
                              hipStream_t stream)
{
  (void)in_sizes; (void)n_in; (void)out_size; (void)ws_size;
  const float* queries = (const float*)d_in[0];
  const float* feats   = (const float*)d_in[1];
  const float* Wq = (const float*)d_in[2];
  const float* bq = (const float*)d_in[3];
  const float* Wk = (const float*)d_in[4];
  const float* bk = (const float*)d_in[5];
  const float* Wv = (const float*)d_in[6];
  const float* bv = (const float*)d_in[7];
  const float* W1 = (const float*)d_in[8];
  const float* b1 = (const float*)d_in[9];
  const float* gamma = (const float*)d_in[10];
  const float* beta  = (const float*)d_in[11];
  const float* W2 = (const float*)d_in[12];
  const float* b2 = (const float*)d_in[13];

  const int N = N_PTS, B = NBATCH;
  const int NCq = N * 4;    // 32768 cols (n,r)
  const int NCf = N * 16;   // 131072 cols (n,k)

  // workspace layout (bytes): q 64Mi | k 256Mi | v 256Mi | aggF 128Mi | stats 8K
  // h1 (128Mi bf16) aliases the dead q+k region after attention.
  char* ws = (char*)d_ws;
  u16*   qb    = (u16*)(ws);
  u16*   kb    = (u16*)(ws + 67108864L);
  u16*   vb    = (u16*)(ws + 335544320L);
  float* aggF  = (float*)(ws + 603979776L);
  float* stats = (float*)(ws + 738197504L);   // sum[512],sq[512],scale[512],shift[512]
  u16*   h1b   = (u16*)(ws);
  float* scale = stats + 1024;
  float* shift = stats + 1536;

  zero_k<<<dim3(4), 256, 0, stream>>>(stats);

  // q = Wq @ queries + bq   -> bf16
  gemm_k<0, 256><<<dim3(NCq/128, 2, B), 256, 0, stream>>>(
      Wq, Wq, bq, bq, 1 << 30,
      queries, (long)256*NCq, NCq,
      qb, (long)256*NCq, nullptr, 0,
      nullptr, nullptr, nullptr, nullptr, nullptr, 0, nullptr, 0);

  // [k;v] = [Wk;Wv] @ feats + [bk;bv]  -> bf16 (row-split outputs)
  gemm_k<0, 256><<<dim3(NCf/128, 4, B), 256, 0, stream>>>(
      Wk, Wv, bk, bv, 256,
      feats, (long)256*NCf, NCf,
      kb, (long)256*NCf, vb, (long)256*NCf,
      nullptr, nullptr, nullptr, nullptr, nullptr, 0, nullptr, 0);

  // attention + queries residual -> aggF fp32
  attn_k<<<dim3(N/4, B), 256, 0, stream>>>(qb, kb, vb, queries, aggF);

  // h1 = W1 @ agg + b1 -> bf16, + BN stat partials
  gemm_k<1, 256><<<dim3(NCq/128, 4, B), 256, 0, stream>>>(
      W1, W1, b1, b1, 1 << 30,
      aggF, (long)256*NCq, NCq,
      h1b, (long)512*NCq, nullptr, 0,
      stats, stats + 512, nullptr, nullptr, nullptr, 0, nullptr, 0);

  finalize_k<<<dim3(2), 256, 0, stream>>>(stats, gamma, beta, scale);

  // out = relu(W2 @ relu(bn(h1)) + b2 + agg) -> fp32 d_out
  gemm_k<2, 512><<<dim3(NCq/128, 2, B), 256, 0, stream>>>(
      W2, W2, b2, b2, 1 << 30,
      h1b, (long)512*NCq, NCq,
      nullptr, 0, nullptr, 0,
      nullptr, nullptr, scale, shift,
      aggF, (long)256*NCq, (float*)d_out, (long)256*NCq);
}

// Round 2
// 1321.338 us; speedup vs baseline: 1.1710x; 1.1710x over previous
//
#include <hip/hip_runtime.h>
#include <hip/hip_bf16.h>

#define NB 4
#define NRQ 32768      // per-batch q-side rows  (n*4)
#define NKF 131072     // per-batch feats cols   (n*16)
#define CHPTS 1024     // points per chunk
#define CHROWS 16384   // feats rows per chunk (CHPTS*16)
#define NCHUNK 8

using u16 = unsigned short;
typedef short bf16x8 __attribute__((ext_vector_type(8)));
typedef float f32x4  __attribute__((ext_vector_type(4)));
typedef u16   u16x8  __attribute__((ext_vector_type(8)));
typedef u16   u16x4  __attribute__((ext_vector_type(4)));

__device__ __forceinline__ u16 f2b(float f){
  unsigned u = __float_as_uint(f);
  return (u16)((u + 0x7fffu + ((u >> 16) & 1u)) >> 16);  // RNE
}
__device__ __forceinline__ float b2f(u16 v){
  return __uint_as_float(((unsigned)v) << 16);
}

#define GLOAD16(g, l) __builtin_amdgcn_global_load_lds( \
    (const __attribute__((address_space(1))) unsigned int*)(g), \
    (__attribute__((address_space(3))) unsigned int*)(l), 16, 0, 0)

// ---------------------------------------------------------------------------
// Transpose+convert: in fp32 [B][256][NCtot] cols [col0, col0+rows) ->
// out bf16 [B][rows][256].
// ---------------------------------------------------------------------------
__global__ __launch_bounds__(256) void transpose_k(
    const float* __restrict__ in, u16* __restrict__ out,
    int NCtot, int col0, long outBatch)
{
  __shared__ u16 sT[64][264];
  const int t = threadIdx.x, b = blockIdx.y;
  const int nr0 = blockIdx.x * 64;                  // local out-row base
  const int cb = t >> 2, nrq = t & 3;
  const long ib = (long)b * 256 * NCtot + col0 + nr0;

  #pragma unroll
  for (int ci = 0; ci < 4; ++ci){
    const int c = cb + ci * 64;
    const float* src = in + ib + (long)c * NCtot + nrq * 16;
    #pragma unroll
    for (int j = 0; j < 4; ++j){
      float4 f = *reinterpret_cast<const float4*>(src + j * 4);
      int nr = nrq * 16 + j * 4;
      sT[nr+0][c] = f2b(f.x); sT[nr+1][c] = f2b(f.y);
      sT[nr+2][c] = f2b(f.z); sT[nr+3][c] = f2b(f.w);
    }
  }
  __syncthreads();
  const int row = t >> 2, qtr = t & 3;
  u16* orow = out + (long)b * outBatch + (long)(nr0 + row) * 256 + qtr * 64;
  #pragma unroll
  for (int i = 0; i < 8; ++i)
    *reinterpret_cast<u16x8*>(orow + i * 8) =
        *reinterpret_cast<const u16x8*>(&sT[row][qtr * 64 + i * 8]);
}

// ---------------------------------------------------------------------------
// GEMM: C[rows x NCH] = A[rows x KD] (bf16, k-contig) * W[NCH x KD]^T + bias.
// A staged via global_load_lds (linear LDS dest, pre-swizzled global source);
// W reg-staged fp32->bf16 with the same XOR swizzle. 128x128 tile, BK=64,
// 4 waves (2x2), 16x16x32 bf16 MFMA, XCD-bijective block swizzle (ch inner).
// MODE 0: write bf16 C rows.  MODE 1: + per-channel sum/sumsq atomics.
// MODE 2: RMW fp32 outF (d_out, [ch][row] layout): out=relu(acc+bias+out).
// ---------------------------------------------------------------------------
template<int MODE, int KD>
__global__ __launch_bounds__(256) void gemm_k(
    const u16* __restrict__ A, long aBatch, int chTiles,
    const float* __restrict__ WA, const float* __restrict__ WB, int splitCh,
    const float* __restrict__ bA, const float* __restrict__ bB,
    u16* __restrict__ outH, long oBatch, int NCH,
    float* __restrict__ statSum, float* __restrict__ statSq,
    float* __restrict__ outF, long fBatch)
{
  __shared__ __align__(16) char sA[16384];   // [128 rows][64 k] bf16 (phys swz)
  __shared__ __align__(16) char sB[16384];   // [128 ch  ][64 k] bf16 (swz)

  const int t = threadIdx.x, lane = t & 63, wid = t >> 6;
  const int wm = wid >> 1, wn = wid & 1;
  const int b = blockIdx.z;

  // XCD-aware bijective swizzle; tile order row-major (ch-tile inner) so one
  // XCD's in-flight blocks share A panels in its L2.
  const int nwg = gridDim.x, orig = blockIdx.x;
  const int qq = nwg >> 3, rr = nwg & 7, xcd = orig & 7, pos = orig >> 3;
  const int wg = (xcd < rr ? xcd * (qq + 1) : rr * (qq + 1) + (xcd - rr) * qq) + pos;
  const int rowT = wg / chTiles, chT = wg % chTiles;

  const u16* Ab = A + (long)b * aBatch + (long)rowT * 128 * KD;

  f32x4 acc[4][4];
  #pragma unroll
  for (int i = 0; i < 4; ++i)
    #pragma unroll
    for (int j = 0; j < 4; ++j) acc[i][j] = (f32x4){0.f,0.f,0.f,0.f};

  const int wrow = t >> 1, whalf = t & 1;
  const int chg = chT * 128 + wrow;
  const float* Wp = (chg < splitCh) ? WA + (long)chg * KD
                                    : WB + (long)(chg - splitCh) * KD;
  const int sub = lane >> 3, kc = (lane & 7) ^ sub;   // source pre-swizzle

  for (int ks = 0; ks < KD / 64; ++ks){
    const int k0 = ks * 64;
    // ---- A: 16 chunks x 1KB via global_load_lds (4 per wave)
    #pragma unroll
    for (int i = 0; i < 4; ++i){
      const int chunk = wid * 4 + i;
      const u16* src = Ab + (long)(chunk * 8 + sub) * KD + k0 + kc * 8;
      GLOAD16(src, sA + chunk * 1024);
    }
    // ---- B: weights fp32 -> bf16, swizzled vector stores
    {
      const float4* wsrc = reinterpret_cast<const float4*>(Wp + k0 + whalf * 32);
      #pragma unroll
      for (int i = 0; i < 4; ++i){
        float4 fa = wsrc[2*i], fb = wsrc[2*i+1];
        u16x8 pk;
        pk[0]=f2b(fa.x); pk[1]=f2b(fa.y); pk[2]=f2b(fa.z); pk[3]=f2b(fa.w);
        pk[4]=f2b(fb.x); pk[5]=f2b(fb.y); pk[6]=f2b(fb.z); pk[7]=f2b(fb.w);
        int bo = (wrow*128 + whalf*64 + i*16) ^ ((wrow & 7) << 4);
        *reinterpret_cast<u16x8*>(sB + bo) = pk;
      }
    }
    __syncthreads();
    #pragma unroll
    for (int kk = 0; kk < 2; ++kk){
      bf16x8 af[4], bf[4];
      #pragma unroll
      for (int mi = 0; mi < 4; ++mi){
        int m = wm*64 + mi*16 + (lane & 15);
        af[mi] = *reinterpret_cast<const bf16x8*>(
            sA + ((m*128 + kk*64 + (lane>>4)*16) ^ ((m & 7) << 4)));
      }
      #pragma unroll
      for (int ni = 0; ni < 4; ++ni){
        int c = wn*64 + ni*16 + (lane & 15);
        bf[ni] = *reinterpret_cast<const bf16x8*>(
            sB + ((c*128 + kk*64 + (lane>>4)*16) ^ ((c & 7) << 4)));
      }
      #pragma unroll
      for (int mi = 0; mi < 4; ++mi)
        #pragma unroll
        for (int ni = 0; ni < 4; ++ni)
          acc[mi][ni] = __builtin_amdgcn_mfma_f32_16x16x32_bf16(
              af[mi], bf[ni], acc[mi][ni], 0, 0, 0);
    }
    __syncthreads();
  }

  // ---- epilogue (C rows from A-index, cols from W-index)
  int chI[4]; float bv[4];
  #pragma unroll
  for (int ni = 0; ni < 4; ++ni){
    int ch = chT*128 + wn*64 + ni*16 + (lane & 15);
    chI[ni] = ch;
    bv[ni] = (ch < splitCh) ? bA[ch] : bB[ch - splitCh];
  }
  if (MODE <= 1){
    float s[4] = {0,0,0,0}, sq[4] = {0,0,0,0};
    u16* outb = outH + (long)b * oBatch;
    #pragma unroll
    for (int mi = 0; mi < 4; ++mi){
      #pragma unroll
      for (int j = 0; j < 4; ++j){
        const long row = rowT*128 + wm*64 + mi*16 + (lane>>4)*4 + j;
        #pragma unroll
        for (int ni = 0; ni < 4; ++ni){
          float v = acc[mi][ni][j] + bv[ni];
          outb[row * NCH + chI[ni]] = f2b(v);
          if (MODE == 1){ s[ni] += v; sq[ni] += v * v; }
        }
      }
    }
    if (MODE == 1){
      #pragma unroll
      for (int ni = 0; ni < 4; ++ni){
        s[ni]  += __shfl_xor(s[ni], 16);  s[ni]  += __shfl_xor(s[ni], 32);
        sq[ni] += __shfl_xor(sq[ni], 16); sq[ni] += __shfl_xor(sq[ni], 32);
      }
      if (lane < 16){
        #pragma unroll
        for (int ni = 0; ni < 4; ++ni){
          atomicAdd(&statSum[chI[ni]], s[ni]);
          atomicAdd(&statSq[chI[ni]],  sq[ni]);
        }
      }
    }
  } else {
    #pragma unroll
    for (int mi = 0; mi < 4; ++mi){
      const int nr0 = rowT*128 + wm*64 + mi*16 + (lane>>4)*4;
      #pragma unroll
      for (int ni = 0; ni < 4; ++ni){
        float* op = outF + (long)b * fBatch + (long)chI[ni] * NRQ + nr0;
        float4 r4 = *reinterpret_cast<const float4*>(op);
        float4 o;
        o.x = fmaxf(acc[mi][ni][0] + bv[ni] + r4.x, 0.f);
        o.y = fmaxf(acc[mi][ni][1] + bv[ni] + r4.y, 0.f);
        o.z = fmaxf(acc[mi][ni][2] + bv[ni] + r4.z, 0.f);
        o.w = fmaxf(acc[mi][ni][3] + bv[ni] + r4.w, 0.f);
        *reinterpret_cast<float4*>(op) = o;
      }
    }
  }
}

// ---------------------------------------------------------------------------
// Attention (chunked): qT full [B][NRQ][256] bf16; kv chunk [B][CHROWS][512]
// (ch 0-255 = k, 256-511 = v). Writes aggT bf16 [B][NRQ][256] and fp32
// residual agg into d_out [B][256][NRQ]. 4 points/block, wave = point.
// ---------------------------------------------------------------------------
__global__ __launch_bounds__(256) void attn_k(
    const u16* __restrict__ qT, const u16* __restrict__ kv,
    const float* __restrict__ queries,
    u16* __restrict__ aggT, float* __restrict__ aggR, int n0chunk)
{
  __shared__ __align__(16) float sQ[4][4][256];
  __shared__ __align__(16) float sS[4][4][16][4];
  const int t = threadIdx.x, b = blockIdx.y;
  const int nloc0 = blockIdx.x * 4;
  const long nglob0 = n0chunk + nloc0;

  // stage q rows as fp32
  #pragma unroll
  for (int it = 0; it < 2; ++it){
    int item = it * 256 + t;
    int rw = item >> 5, c16 = item & 31;
    u16x8 v = *reinterpret_cast<const u16x8*>(
        qT + ((long)b * NRQ + (nglob0 + (rw >> 2)) * 4 + (rw & 3)) * 256 + c16 * 8);
    float4 f0, f1;
    f0.x=b2f(v[0]); f0.y=b2f(v[1]); f0.z=b2f(v[2]); f0.w=b2f(v[3]);
    f1.x=b2f(v[4]); f1.y=b2f(v[5]); f1.z=b2f(v[6]); f1.w=b2f(v[7]);
    *reinterpret_cast<float4*>(&sQ[rw>>2][rw&3][c16*8])     = f0;
    *reinterpret_cast<float4*>(&sQ[rw>>2][rw&3][c16*8 + 4]) = f1;
  }
  __syncthreads();

  // phase A: logits + softmax; thread = (p, h, kk)
  {
    const int p = t >> 6, h = (t >> 4) & 3, kk = t & 15;
    const u16* krow = kv + ((long)b*CHROWS + (long)(nloc0+p)*16 + kk)*512 + h*64;
    float l[4] = {0.f,0.f,0.f,0.f};
    #pragma unroll
    for (int d8 = 0; d8 < 8; ++d8){
      u16x8 kw = *reinterpret_cast<const u16x8*>(krow + d8 * 8);
      float kf[8];
      #pragma unroll
      for (int e = 0; e < 8; ++e) kf[e] = b2f(kw[e]);
      #pragma unroll
      for (int r = 0; r < 4; ++r){
        const float* qp = &sQ[p][r][h*64 + d8*8];
        float4 qa = *reinterpret_cast<const float4*>(qp);
        float4 qb = *reinterpret_cast<const float4*>(qp + 4);
        l[r] += kf[0]*qa.x + kf[1]*qa.y + kf[2]*qa.z + kf[3]*qa.w
              + kf[4]*qb.x + kf[5]*qb.y + kf[6]*qb.z + kf[7]*qb.w;
      }
    }
    float4 prob;
    #pragma unroll
    for (int r = 0; r < 4; ++r){
      float x = l[r] * 0.125f;
      float m = x;
      #pragma unroll
      for (int off = 1; off < 16; off <<= 1) m = fmaxf(m, __shfl_xor(m, off));
      float e = __expf(x - m);
      float ssum = e;
      #pragma unroll
      for (int off = 1; off < 16; off <<= 1) ssum += __shfl_xor(ssum, off);
      float pr = e / ssum;
      if (r == 0) prob.x = pr; else if (r == 1) prob.y = pr;
      else if (r == 2) prob.z = pr; else prob.w = pr;
    }
    *reinterpret_cast<float4*>(&sS[p][h][kk][0]) = prob;
  }
  __syncthreads();

  // phase B: agg = v @ soft^T + queries residual; thread = (p, 4-ch group)
  {
    const int p = t >> 6, c4 = t & 63, ch0 = c4 * 4, h = c4 >> 4;
    const u16* vbase = kv + ((long)b*CHROWS + (long)(nloc0+p)*16)*512 + 256 + ch0;
    float a[4][4] = {};                       // [r][cc]
    #pragma unroll
    for (int kk = 0; kk < 16; ++kk){
      u16x4 vv = *reinterpret_cast<const u16x4*>(vbase + (long)kk * 512);
      float4 sv = *reinterpret_cast<const float4*>(&sS[p][h][kk][0]);
      #pragma unroll
      for (int cc = 0; cc < 4; ++cc){
        float vf = b2f(vv[cc]);
        a[0][cc] += sv.x*vf; a[1][cc] += sv.y*vf;
        a[2][cc] += sv.z*vf; a[3][cc] += sv.w*vf;
      }
    }
    const long nq = nglob0 + p;
    float qv[4][4];                           // [cc][r]
    #pragma unroll
    for (int cc = 0; cc < 4; ++cc){
      float4 q4 = *reinterpret_cast<const float4*>(
          queries + ((long)b*256 + ch0 + cc) * NRQ + nq * 4);
      qv[cc][0]=q4.x; qv[cc][1]=q4.y; qv[cc][2]=q4.z; qv[cc][3]=q4.w;
    }
    #pragma unroll
    for (int cc = 0; cc < 4; ++cc){
      float4 o;
      o.x = a[0][cc]+qv[cc][0]; o.y = a[1][cc]+qv[cc][1];
      o.z = a[2][cc]+qv[cc][2]; o.w = a[3][cc]+qv[cc][3];
      *reinterpret_cast<float4*>(aggR + ((long)b*256 + ch0 + cc)*NRQ + nq*4) = o;
    }
    #pragma unroll
    for (int r = 0; r < 4; ++r){
      u16x4 pk;
      #pragma unroll
      for (int cc = 0; cc < 4; ++cc) pk[cc] = f2b(a[r][cc] + qv[cc][r]);
      *reinterpret_cast<u16x4*>(aggT + ((long)b*NRQ + nq*4 + r)*256 + ch0) = pk;
    }
  }
}

// ---------------------------------------------------------------------------
__global__ void bnrelu_k(u16* __restrict__ h1, const float* __restrict__ sc,
                         const float* __restrict__ sh)
{
  const long total = (long)NB * NRQ * 512 / 8;
  for (long i = (long)blockIdx.x * blockDim.x + threadIdx.x; i < total;
       i += (long)gridDim.x * blockDim.x){
    u16x8 v = *reinterpret_cast<const u16x8*>(h1 + i * 8);
    int chb = (int)((i * 8) & 511);
    float4 s0 = *reinterpret_cast<const float4*>(sc + chb);
    float4 s1 = *reinterpret_cast<const float4*>(sc + chb + 4);
    float4 h0 = *reinterpret_cast<const float4*>(sh + chb);
    float4 h1v= *reinterpret_cast<const float4*>(sh + chb + 4);
    u16x8 o;
    o[0]=f2b(fmaxf(b2f(v[0])*s0.x+h0.x ,0.f)); o[1]=f2b(fmaxf(b2f(v[1])*s0.y+h0.y ,0.f));
    o[2]=f2b(fmaxf(b2f(v[2])*s0.z+h0.z ,0.f)); o[3]=f2b(fmaxf(b2f(v[3])*s0.w+h0.w ,0.f));
    o[4]=f2b(fmaxf(b2f(v[4])*s1.x+h1v.x,0.f)); o[5]=f2b(fmaxf(b2f(v[5])*s1.y+h1v.y,0.f));
    o[6]=f2b(fmaxf(b2f(v[6])*s1.z+h1v.z,0.f)); o[7]=f2b(fmaxf(b2f(v[7])*s1.w+h1v.w,0.f));
    *reinterpret_cast<u16x8*>(h1 + i * 8) = o;
  }
}

__global__ void zero_k(float* p){ p[blockIdx.x*256 + threadIdx.x] = 0.f; }

__global__ void finalize_k(const float* __restrict__ st,
                           const float* __restrict__ gamma,
                           const float* __restrict__ beta,
                           float* __restrict__ out)   // scale[512], shift[512]
{
  int o = blockIdx.x*256 + threadIdx.x;
  const float inv = 1.f / 131072.f;                   // B*N*R
  float mean = st[o] * inv;
  float var  = st[512 + o] * inv - mean*mean;
  float sc   = gamma[o] * rsqrtf(var + 1e-5f);
  out[o]       = sc;
  out[512 + o] = beta[o] - mean * sc;
}

// ---------------------------------------------------------------------------
extern "C" void kernel_launch(void* const* d_in, const int* in_sizes, int n_in,
                              void* d_out, int out_size, void* d_ws, size_t ws_size,
                              hipStream_t stream)
{
  (void)in_sizes; (void)n_in; (void)out_size; (void)ws_size;
  const float* queries = (const float*)d_in[0];
  const float* feats   = (const float*)d_in[1];
  const float* Wq = (const float*)d_in[2];
  const float* bq = (const float*)d_in[3];
  const float* Wk = (const float*)d_in[4];
  const float* bk = (const float*)d_in[5];
  const float* Wv = (const float*)d_in[6];
  const float* bv = (const float*)d_in[7];
  const float* W1 = (const float*)d_in[8];
  const float* b1 = (const float*)d_in[9];
  const float* gamma = (const float*)d_in[10];
  const float* beta  = (const float*)d_in[11];
  const float* W2 = (const float*)d_in[12];
  const float* b2 = (const float*)d_in[13];

  // ws layout (bytes):
  //   [0, 134.2M)   : fT chunk (33.5M) during chunks; h1T (134.2M) after
  //   [134.2M, 201M): kv chunk (67.1M); earlier overlaid by qrT (dead after q-GEMM)
  //   [201M, 268M)  : aggT bf16 (67.1M)
  //   [268M, 335M)  : qT bf16 (67.1M)
  //   [335.5M, +4K) : stats
  char* ws = (char*)d_ws;
  u16*   fT    = (u16*)ws;
  u16*   h1T   = (u16*)ws;
  u16*   kvB   = (u16*)(ws + 134217728L);
  u16*   qrT   = (u16*)(ws + 134217728L);
  u16*   aggT  = (u16*)(ws + 201326592L);
  u16*   qT    = (u16*)(ws + 268435456L);
  float* stats = (float*)(ws + 335544320L);
  float* scale = stats + 1024;
  float* shift = stats + 1536;
  float* aggR  = (float*)d_out;

  zero_k<<<dim3(4), 256, 0, stream>>>(stats);

  // queries -> qrT bf16 [B][NRQ][256]
  transpose_k<<<dim3(NRQ/64, NB), 256, 0, stream>>>(queries, qrT, NRQ, 0, (long)NRQ*256);

  // qT = qrT @ Wq^T + bq
  gemm_k<0, 256><<<dim3(512, 1, NB), 256, 0, stream>>>(
      qrT, (long)NRQ*256, 2, Wq, Wq, 1<<30, bq, bq,
      qT, (long)NRQ*256, 256, nullptr, nullptr, nullptr, 0);

  for (int c = 0; c < NCHUNK; ++c){
    transpose_k<<<dim3(CHROWS/64, NB), 256, 0, stream>>>(
        feats, fT, NKF, c*CHROWS, (long)CHROWS*256);
    gemm_k<0, 256><<<dim3(512, 1, NB), 256, 0, stream>>>(
        fT, (long)CHROWS*256, 4, Wk, Wv, 256, bk, bv,
        kvB, (long)CHROWS*512, 512, nullptr, nullptr, nullptr, 0);
    attn_k<<<dim3(CHPTS/4, NB), 256, 0, stream>>>(
        qT, kvB, queries, aggT, aggR, c*CHPTS);
  }

  // h1 = aggT @ W1^T + b1 -> bf16 + BN stats
  gemm_k<1, 256><<<dim3(1024, 1, NB), 256, 0, stream>>>(
      aggT, (long)NRQ*256, 4, W1, W1, 1<<30, b1, b1,
      h1T, (long)NRQ*512, 512, stats, stats + 512, nullptr, 0);

  finalize_k<<<dim3(2), 256, 0, stream>>>(stats, gamma, beta, scale);

  // h1 <- relu(bn(h1)) in place
  bnrelu_k<<<dim3(2048), 256, 0, stream>>>(h1T, scale, shift);

  // d_out = relu(h1' @ W2^T + b2 + agg)   (agg fp32 already in d_out)
  gemm_k<2, 512><<<dim3(512, 1, NB), 256, 0, stream>>>(
      h1T, (long)NRQ*512, 2, W2, W2, 1<<30, b2, b2,
      nullptr, 0, 256, nullptr, nullptr, aggR, (long)256*NRQ);
}

// Round 3
// 1062.196 us; speedup vs baseline: 1.4566x; 1.2440x over previous
//
#include <hip/hip_runtime.h>
#include <hip/hip_bf16.h>

#define NB 4
#define NRQ 32768      // per-batch q-side rows  (n*4)
#define NKF 131072     // per-batch feats cols   (n*16)
#define CHPTS 1024     // points per chunk
#define CHROWS 16384   // feats rows per chunk (CHPTS*16)
#define NCHUNK 8

using u16 = unsigned short;
typedef short bf16x8 __attribute__((ext_vector_type(8)));
typedef float f32x4  __attribute__((ext_vector_type(4)));
typedef u16   u16x8  __attribute__((ext_vector_type(8)));
typedef u16   u16x4  __attribute__((ext_vector_type(4)));

__device__ __forceinline__ u16 f2b(float f){
  unsigned u = __float_as_uint(f);
  return (u16)((u + 0x7fffu + ((u >> 16) & 1u)) >> 16);  // RNE
}
__device__ __forceinline__ float b2f(u16 v){
  return __uint_as_float(((unsigned)v) << 16);
}

#define GLOAD16(g, l) __builtin_amdgcn_global_load_lds( \
    (const __attribute__((address_space(1))) unsigned int*)(g), \
    (__attribute__((address_space(3))) unsigned int*)(l), 16, 0, 0)

// ---------------------------------------------------------------------------
// Weight preconvert fp32 -> bf16 (k-contiguous rows, stacked):
//   wT elems: [0,65536) Wk | [65536,131072) Wv | [131072,196608) Wq |
//             [196608,327680) W1 | [327680,458752) W2
// ---------------------------------------------------------------------------
__global__ __launch_bounds__(256) void cvtW_k(
    const float* __restrict__ Wk, const float* __restrict__ Wv,
    const float* __restrict__ Wq, const float* __restrict__ W1,
    const float* __restrict__ W2, u16* __restrict__ wT)
{
  long e = ((long)blockIdx.x * 256 + threadIdx.x) * 8;
  const float* src; long off;
  if      (e < 65536)  { src = Wk; off = e; }
  else if (e < 131072) { src = Wv; off = e - 65536; }
  else if (e < 196608) { src = Wq; off = e - 131072; }
  else if (e < 327680) { src = W1; off = e - 196608; }
  else                 { src = W2; off = e - 327680; }
  float4 f0 = *reinterpret_cast<const float4*>(src + off);
  float4 f1 = *reinterpret_cast<const float4*>(src + off + 4);
  u16x8 p;
  p[0]=f2b(f0.x); p[1]=f2b(f0.y); p[2]=f2b(f0.z); p[3]=f2b(f0.w);
  p[4]=f2b(f1.x); p[5]=f2b(f1.y); p[6]=f2b(f1.z); p[7]=f2b(f1.w);
  *reinterpret_cast<u16x8*>(wT + e) = p;
}

// bias stack [bk;bv] + zero BN stat accumulators
__global__ void prep_k(const float* __restrict__ bk, const float* __restrict__ bv,
                       float* __restrict__ bKV, float* __restrict__ stats)
{
  int i = blockIdx.x * 256 + threadIdx.x;       // grid 6*256 = 1536
  if (i < 512)       bKV[i] = (i < 256) ? bk[i] : bv[i - 256];
  else               stats[i - 512] = 0.f;      // 1024 floats: sum, sumsq
}

// ---------------------------------------------------------------------------
// Transpose+convert: in fp32 [B][256][NCtot] cols [col0, col0+rows) ->
// out bf16 [B][rows][256].
// ---------------------------------------------------------------------------
__global__ __launch_bounds__(256) void transpose_k(
    const float* __restrict__ in, u16* __restrict__ out,
    int NCtot, int col0, long outBatch)
{
  __shared__ u16 sT[64][264];
  const int t = threadIdx.x, b = blockIdx.y;
  const int nr0 = blockIdx.x * 64;
  const int cb = t >> 2, nrq = t & 3;
  const long ib = (long)b * 256 * NCtot + col0 + nr0;

  #pragma unroll
  for (int ci = 0; ci < 4; ++ci){
    const int c = cb + ci * 64;
    const float* src = in + ib + (long)c * NCtot + nrq * 16;
    #pragma unroll
    for (int j = 0; j < 4; ++j){
      float4 f = *reinterpret_cast<const float4*>(src + j * 4);
      int nr = nrq * 16 + j * 4;
      sT[nr+0][c] = f2b(f.x); sT[nr+1][c] = f2b(f.y);
      sT[nr+2][c] = f2b(f.z); sT[nr+3][c] = f2b(f.w);
    }
  }
  __syncthreads();
  const int row = t >> 2, qtr = t & 3;
  u16* orow = out + (long)b * outBatch + (long)(nr0 + row) * 256 + qtr * 64;
  #pragma unroll
  for (int i = 0; i < 8; ++i)
    *reinterpret_cast<u16x8*>(orow + i * 8) =
        *reinterpret_cast<const u16x8*>(&sT[row][qtr * 64 + i * 8]);
}

// ---------------------------------------------------------------------------
// GEMM: C[rows x NCH] = A[rows x KD] (bf16 k-contig) * Wb[NCH x KD]^T + bias.
// Both operands staged via global_load_lds (pre-swizzled source, XOR-swizzled
// reads). 2-phase double-buffered pipeline: STAGE(next) issued before compute.
// 128x128 tile, BK=64, 4 waves (2x2), 16x16x32 bf16 MFMA, XCD swizzle.
// MODE 0: bf16 C. MODE 1: + per-ch sum/sumsq atomics. MODE 2: RMW fp32 outF
// ([ch][row] layout): out = relu(acc + bias + out).
// ---------------------------------------------------------------------------
template<int MODE, int KD>
__global__ __launch_bounds__(256) void gemm_k(
    const u16* __restrict__ A, long aBatch, int chTiles,
    const u16* __restrict__ Wb, const float* __restrict__ bias,
    u16* __restrict__ outH, long oBatch, int NCH,
    float* __restrict__ statSum, float* __restrict__ statSq,
    float* __restrict__ outF, long fBatch)
{
  __shared__ __align__(16) char sA[2][16384];  // [128 rows][64 k] bf16 (swz)
  __shared__ __align__(16) char sB[2][16384];  // [128 ch  ][64 k] bf16 (swz)

  const int t = threadIdx.x, lane = t & 63, wid = t >> 6;
  const int wm = wid >> 1, wn = wid & 1;
  const int b = blockIdx.z;

  // XCD-aware bijective swizzle (ch-tile inner)
  const int nwg = gridDim.x, orig = blockIdx.x;
  const int qq = nwg >> 3, rr = nwg & 7, xcd = orig & 7, pos = orig >> 3;
  const int wg = (xcd < rr ? xcd * (qq + 1) : rr * (qq + 1) + (xcd - rr) * qq) + pos;
  const int rowT = wg / chTiles, chT = wg % chTiles;

  const u16* Ab = A + (long)b * aBatch + (long)rowT * 128 * KD;
  const u16* Wt = Wb + (long)chT * 128 * KD;
  const int sub = lane >> 3, kc8 = ((lane & 7) ^ sub) * 8;  // source pre-swizzle

  f32x4 acc[4][4];
  #pragma unroll
  for (int i = 0; i < 4; ++i)
    #pragma unroll
    for (int j = 0; j < 4; ++j) acc[i][j] = (f32x4){0.f,0.f,0.f,0.f};

  auto STAGE = [&](int buf, int ks){
    const int k0 = ks * 64;
    #pragma unroll
    for (int i = 0; i < 4; ++i){
      const int chunk = wid * 4 + i;
      GLOAD16(Ab + (long)(chunk*8 + sub)*KD + k0 + kc8, sA[buf] + chunk*1024);
      GLOAD16(Wt + (long)(chunk*8 + sub)*KD + k0 + kc8, sB[buf] + chunk*1024);
    }
  };

  constexpr int NT = KD / 64;
  STAGE(0, 0);
  __syncthreads();                 // drains vmcnt; buf0 ready
  int cur = 0;
  for (int ks = 0; ks < NT; ++ks){
    if (ks + 1 < NT) STAGE(cur ^ 1, ks + 1);   // prefetch overlaps compute
    const char* pA = sA[cur]; const char* pB = sB[cur];
    #pragma unroll
    for (int kk = 0; kk < 2; ++kk){
      bf16x8 af[4], bf[4];
      #pragma unroll
      for (int mi = 0; mi < 4; ++mi){
        int m = wm*64 + mi*16 + (lane & 15);
        af[mi] = *reinterpret_cast<const bf16x8*>(
            pA + ((m*128 + kk*64 + (lane>>4)*16) ^ ((m & 7) << 4)));
      }
      #pragma unroll
      for (int ni = 0; ni < 4; ++ni){
        int c = wn*64 + ni*16 + (lane & 15);
        bf[ni] = *reinterpret_cast<const bf16x8*>(
            pB + ((c*128 + kk*64 + (lane>>4)*16) ^ ((c & 7) << 4)));
      }
      #pragma unroll
      for (int mi = 0; mi < 4; ++mi)
        #pragma unroll
        for (int ni = 0; ni < 4; ++ni)
          acc[mi][ni] = __builtin_amdgcn_mfma_f32_16x16x32_bf16(
              af[mi], bf[ni], acc[mi][ni], 0, 0, 0);
    }
    __syncthreads();               // next buffer staged + this one free
    cur ^= 1;
  }

  // ---- epilogue (C/D: col = lane&15, row = (lane>>4)*4 + j)
  int chI[4]; float bv[4];
  #pragma unroll
  for (int ni = 0; ni < 4; ++ni){
    int ch = chT*128 + wn*64 + ni*16 + (lane & 15);
    chI[ni] = ch;
    bv[ni] = bias[ch];
  }
  if (MODE <= 1){
    float s[4] = {0,0,0,0}, sq[4] = {0,0,0,0};
    u16* outb = outH + (long)b * oBatch;
    #pragma unroll
    for (int mi = 0; mi < 4; ++mi){
      #pragma unroll
      for (int j = 0; j < 4; ++j){
        const long row = rowT*128 + wm*64 + mi*16 + (lane>>4)*4 + j;
        #pragma unroll
        for (int ni = 0; ni < 4; ++ni){
          float v = acc[mi][ni][j] + bv[ni];
          outb[row * NCH + chI[ni]] = f2b(v);
          if (MODE == 1){ s[ni] += v; sq[ni] += v * v; }
        }
      }
    }
    if (MODE == 1){
      #pragma unroll
      for (int ni = 0; ni < 4; ++ni){
        s[ni]  += __shfl_xor(s[ni], 16);  s[ni]  += __shfl_xor(s[ni], 32);
        sq[ni] += __shfl_xor(sq[ni], 16); sq[ni] += __shfl_xor(sq[ni], 32);
      }
      if (lane < 16){
        #pragma unroll
        for (int ni = 0; ni < 4; ++ni){
          atomicAdd(&statSum[chI[ni]], s[ni]);
          atomicAdd(&statSq[chI[ni]],  sq[ni]);
        }
      }
    }
  } else {
    #pragma unroll
    for (int mi = 0; mi < 4; ++mi){
      const int nr0 = rowT*128 + wm*64 + mi*16 + (lane>>4)*4;
      #pragma unroll
      for (int ni = 0; ni < 4; ++ni){
        float* op = outF + (long)b * fBatch + (long)chI[ni] * NRQ + nr0;
        float4 r4 = *reinterpret_cast<const float4*>(op);
        float4 o;
        o.x = fmaxf(acc[mi][ni][0] + bv[ni] + r4.x, 0.f);
        o.y = fmaxf(acc[mi][ni][1] + bv[ni] + r4.y, 0.f);
        o.z = fmaxf(acc[mi][ni][2] + bv[ni] + r4.z, 0.f);
        o.w = fmaxf(acc[mi][ni][3] + bv[ni] + r4.w, 0.f);
        *reinterpret_cast<float4*>(op) = o;
      }
    }
  }
}

// ---------------------------------------------------------------------------
// Attention (chunked): qT [B][NRQ][256] bf16; kv chunk rows [pt*16+kk][512]
// (ch 0-255 = k, 256-511 = v). 4 points/block, wave = point. K-half staged in
// LDS via global_load_lds (swizzled); V read direct (contiguous per kk).
// ---------------------------------------------------------------------------
__global__ __launch_bounds__(256) void attn_k(
    const u16* __restrict__ qT, const u16* __restrict__ kv,
    const float* __restrict__ queries,
    u16* __restrict__ aggT, float* __restrict__ aggR, int n0chunk)
{
  __shared__ __align__(16) char  sK[4][8192];    // [kk 16][256 ch] bf16, swz
  __shared__ __align__(16) float sQ[4][4][256];
  __shared__ __align__(16) float sS[4][4][16][4];
  const int t = threadIdx.x, b = blockIdx.y;
  const int lane = t & 63, p = t >> 6;
  const int nloc0 = blockIdx.x * 4;
  const long nglob0 = (long)n0chunk + nloc0;

  // ---- stage K half: 8 chunks x 1KB, source pre-swizzled so LDS read
  // addr = (kk*512 + off) ^ ((kk&7)<<4) is bank-spread.
  {
    const u16* kbase = kv + ((long)b*CHROWS + (long)(nloc0 + p)*16) * 512;
    #pragma unroll
    for (int i = 0; i < 8; ++i){
      const int kkrow = 2*i + (lane >> 5);
      const u16* src = kbase + (long)kkrow*512 + (((lane & 31) ^ (kkrow & 7)) * 8);
      GLOAD16(src, sK[p] + i * 1024);
    }
  }
  // ---- stage Q rows as fp32
  #pragma unroll
  for (int it = 0; it < 2; ++it){
    int item = it * 256 + t;
    int rw = item >> 5, c16 = item & 31;
    u16x8 v = *reinterpret_cast<const u16x8*>(
        qT + ((long)b * NRQ + (nglob0 + (rw >> 2)) * 4 + (rw & 3)) * 256 + c16 * 8);
    float4 f0, f1;
    f0.x=b2f(v[0]); f0.y=b2f(v[1]); f0.z=b2f(v[2]); f0.w=b2f(v[3]);
    f1.x=b2f(v[4]); f1.y=b2f(v[5]); f1.z=b2f(v[6]); f1.w=b2f(v[7]);
    *reinterpret_cast<float4*>(&sQ[rw>>2][rw&3][c16*8])     = f0;
    *reinterpret_cast<float4*>(&sQ[rw>>2][rw&3][c16*8 + 4]) = f1;
  }
  __syncthreads();

  // ---- phase A: logits + softmax; lane = (h, kk) within wave p
  {
    const int h = (lane >> 4) & 3, kk = lane & 15;
    float l[4] = {0.f,0.f,0.f,0.f};
    #pragma unroll
    for (int d8 = 0; d8 < 8; ++d8){
      u16x8 kw = *reinterpret_cast<const u16x8*>(
          sK[p] + ((kk*512 + h*128 + d8*16) ^ ((kk & 7) << 4)));
      float kf[8];
      #pragma unroll
      for (int e = 0; e < 8; ++e) kf[e] = b2f(kw[e]);
      #pragma unroll
      for (int r = 0; r < 4; ++r){
        const float* qp = &sQ[p][r][h*64 + d8*8];
        float4 qa = *reinterpret_cast<const float4*>(qp);
        float4 qb = *reinterpret_cast<const float4*>(qp + 4);
        l[r] += kf[0]*qa.x + kf[1]*qa.y + kf[2]*qa.z + kf[3]*qa.w
              + kf[4]*qb.x + kf[5]*qb.y + kf[6]*qb.z + kf[7]*qb.w;
      }
    }
    float4 prob;
    #pragma unroll
    for (int r = 0; r < 4; ++r){
      float x = l[r] * 0.125f;
      float m = x;
      #pragma unroll
      for (int off = 1; off < 16; off <<= 1) m = fmaxf(m, __shfl_xor(m, off));
      float e = __expf(x - m);
      float ssum = e;
      #pragma unroll
      for (int off = 1; off < 16; off <<= 1) ssum += __shfl_xor(ssum, off);
      float pr = e / ssum;
      if (r == 0) prob.x = pr; else if (r == 1) prob.y = pr;
      else if (r == 2) prob.z = pr; else prob.w = pr;
    }
    *reinterpret_cast<float4*>(&sS[p][h][lane & 15][0]) = prob;
  }
  __syncthreads();

  // ---- phase B: agg = v @ soft^T + residual; lane = 4-ch group of wave p
  {
    const int c4 = lane, ch0 = c4 * 4, h = c4 >> 4;
    const u16* vbase = kv + ((long)b*CHROWS + (long)(nloc0 + p)*16)*512 + 256 + ch0;
    float a[4][4] = {};                       // [r][cc]
    #pragma unroll
    for (int kk = 0; kk < 16; ++kk){
      u16x4 vv = *reinterpret_cast<const u16x4*>(vbase + (long)kk * 512);
      float4 sv = *reinterpret_cast<const float4*>(&sS[p][h][kk][0]);
      #pragma unroll
      for (int cc = 0; cc < 4; ++cc){
        float vf = b2f(vv[cc]);
        a[0][cc] += sv.x*vf; a[1][cc] += sv.y*vf;
        a[2][cc] += sv.z*vf; a[3][cc] += sv.w*vf;
      }
    }
    const long nq = nglob0 + p;
    float qv[4][4];                           // [cc][r]
    #pragma unroll
    for (int cc = 0; cc < 4; ++cc){
      float4 q4 = *reinterpret_cast<const float4*>(
          queries + ((long)b*256 + ch0 + cc) * NRQ + nq * 4);
      qv[cc][0]=q4.x; qv[cc][1]=q4.y; qv[cc][2]=q4.z; qv[cc][3]=q4.w;
    }
    #pragma unroll
    for (int cc = 0; cc < 4; ++cc){
      float4 o;
      o.x = a[0][cc]+qv[cc][0]; o.y = a[1][cc]+qv[cc][1];
      o.z = a[2][cc]+qv[cc][2]; o.w = a[3][cc]+qv[cc][3];
      *reinterpret_cast<float4*>(aggR + ((long)b*256 + ch0 + cc)*NRQ + nq*4) = o;
    }
    #pragma unroll
    for (int r = 0; r < 4; ++r){
      u16x4 pk;
      #pragma unroll
      for (int cc = 0; cc < 4; ++cc) pk[cc] = f2b(a[r][cc] + qv[cc][r]);
      *reinterpret_cast<u16x4*>(aggT + ((long)b*NRQ + nq*4 + r)*256 + ch0) = pk;
    }
  }
}

// ---------------------------------------------------------------------------
__global__ void bnrelu_k(u16* __restrict__ h1, const float* __restrict__ sc,
                         const float* __restrict__ sh)
{
  const long total = (long)NB * NRQ * 512 / 8;
  for (long i = (long)blockIdx.x * blockDim.x + threadIdx.x; i < total;
       i += (long)gridDim.x * blockDim.x){
    u16x8 v = *reinterpret_cast<const u16x8*>(h1 + i * 8);
    int chb = (int)((i * 8) & 511);
    float4 s0 = *reinterpret_cast<const float4*>(sc + chb);
    float4 s1 = *reinterpret_cast<const float4*>(sc + chb + 4);
    float4 h0 = *reinterpret_cast<const float4*>(sh + chb);
    float4 h1v= *reinterpret_cast<const float4*>(sh + chb + 4);
    u16x8 o;
    o[0]=f2b(fmaxf(b2f(v[0])*s0.x+h0.x ,0.f)); o[1]=f2b(fmaxf(b2f(v[1])*s0.y+h0.y ,0.f));
    o[2]=f2b(fmaxf(b2f(v[2])*s0.z+h0.z ,0.f)); o[3]=f2b(fmaxf(b2f(v[3])*s0.w+h0.w ,0.f));
    o[4]=f2b(fmaxf(b2f(v[4])*s1.x+h1v.x,0.f)); o[5]=f2b(fmaxf(b2f(v[5])*s1.y+h1v.y,0.f));
    o[6]=f2b(fmaxf(b2f(v[6])*s1.z+h1v.z,0.f)); o[7]=f2b(fmaxf(b2f(v[7])*s1.w+h1v.w,0.f));
    *reinterpret_cast<u16x8*>(h1 + i * 8) = o;
  }
}

__global__ void finalize_k(const float* __restrict__ st,
                           const float* __restrict__ gamma,
                           const float* __restrict__ beta,
                           float* __restrict__ out)   // scale[512], shift[512]
{
  int o = blockIdx.x*256 + threadIdx.x;
  const float inv = 1.f / 131072.f;                   // B*N*R
  float mean = st[o] * inv;
  float var  = st[512 + o] * inv - mean*mean;
  float sc   = gamma[o] * rsqrtf(var + 1e-5f);
  out[o]       = sc;
  out[512 + o] = beta[o] - mean * sc;
}

// ---------------------------------------------------------------------------
extern "C" void kernel_launch(void* const* d_in, const int* in_sizes, int n_in,
                              void* d_out, int out_size, void* d_ws, size_t ws_size,
                              hipStream_t stream)
{
  (void)in_sizes; (void)n_in; (void)out_size; (void)ws_size;
  const float* queries = (const float*)d_in[0];
  const float* feats   = (const float*)d_in[1];
  const float* Wq = (const float*)d_in[2];
  const float* bq = (const float*)d_in[3];
  const float* Wk = (const float*)d_in[4];
  const float* bk = (const float*)d_in[5];
  const float* Wv = (const float*)d_in[6];
  const float* bv = (const float*)d_in[7];
  const float* W1 = (const float*)d_in[8];
  const float* b1 = (const float*)d_in[9];
  const float* gamma = (const float*)d_in[10];
  const float* beta  = (const float*)d_in[11];
  const float* W2 = (const float*)d_in[12];
  const float* b2 = (const float*)d_in[13];

  // ws layout (bytes):
  //   [0, 134.2M)        : fT chunk (33.5M) during chunks; h1T (134.2M) after
  //   [134.2M, 201.3M)   : qrT (dead after q-GEMM), then kvB chunk (67.1M)
  //   [201.3M, 268.4M)   : aggT bf16
  //   [268.4M, 335.5M)   : qT bf16
  //   [335.5M, +8K)      : stats (sum512, sq512, scale512, shift512)
  //   [335.6M, +920K)    : wT bf16 weights + bKV fp32
  char* ws = (char*)d_ws;
  u16*   fT    = (u16*)ws;
  u16*   h1T   = (u16*)ws;
  u16*   qrT   = (u16*)(ws + 134217728L);
  u16*   kvB   = (u16*)(ws + 134217728L);
  u16*   aggT  = (u16*)(ws + 201326592L);
  u16*   qT    = (u16*)(ws + 268435456L);
  float* stats = (float*)(ws + 335544320L);
  float* scale = stats + 1024;
  float* shift = stats + 1536;
  u16*   wT    = (u16*)(ws + 335552512L);
  u16*   wKV   = wT;                 // 512 x 256
  u16*   wQ    = wT + 131072;        // 256 x 256
  u16*   wW1   = wT + 196608;        // 512 x 256
  u16*   wW2   = wT + 327680;        // 256 x 512
  float* bKV   = (float*)(wT + 458752);
  float* aggR  = (float*)d_out;

  cvtW_k<<<dim3(224), 256, 0, stream>>>(Wk, Wv, Wq, W1, W2, wT);
  prep_k<<<dim3(6), 256, 0, stream>>>(bk, bv, bKV, stats);

  // queries -> qrT bf16 [B][NRQ][256]
  transpose_k<<<dim3(NRQ/64, NB), 256, 0, stream>>>(queries, qrT, NRQ, 0, (long)NRQ*256);

  // qT = qrT @ Wq^T + bq
  gemm_k<0, 256><<<dim3(512, 1, NB), 256, 0, stream>>>(
      qrT, (long)NRQ*256, 2, wQ, bq,
      qT, (long)NRQ*256, 256, nullptr, nullptr, nullptr, 0);

  for (int c = 0; c < NCHUNK; ++c){
    transpose_k<<<dim3(CHROWS/64, NB), 256, 0, stream>>>(
        feats, fT, NKF, c*CHROWS, (long)CHROWS*256);
    gemm_k<0, 256><<<dim3(512, 1, NB), 256, 0, stream>>>(
        fT, (long)CHROWS*256, 4, wKV, bKV,
        kvB, (long)CHROWS*512, 512, nullptr, nullptr, nullptr, 0);
    attn_k<<<dim3(CHPTS/4, NB), 256, 0, stream>>>(
        qT, kvB, queries, aggT, aggR, c*CHPTS);
  }

  // h1 = aggT @ W1^T + b1 -> bf16 + BN stats
  gemm_k<1, 256><<<dim3(1024, 1, NB), 256, 0, stream>>>(
      aggT, (long)NRQ*256, 4, wW1, b1,
      h1T, (long)NRQ*512, 512, stats, stats + 512, nullptr, 0);

  finalize_k<<<dim3(2), 256, 0, stream>>>(stats, gamma, beta, scale);

  // h1 <- relu(bn(h1)) in place
  bnrelu_k<<<dim3(2048), 256, 0, stream>>>(h1T, scale, shift);

  // d_out = relu(h1' @ W2^T + b2 + agg)   (agg fp32 already in d_out)
  gemm_k<2, 512><<<dim3(512, 1, NB), 256, 0, stream>>>(
      h1T, (long)NRQ*512, 2, wW2, b2,
      nullptr, 0, 256, nullptr, nullptr, aggR, (long)256*NRQ);
}

// Round 5
// 831.081 us; speedup vs baseline: 1.8617x; 1.2781x over previous
//
#include <hip/hip_runtime.h>
#include <hip/hip_bf16.h>

#define NB 4
#define NRQ 32768      // per-batch q-side rows  (n*4)
#define NKF 131072     // per-batch feats rows   (n*16)

using u16 = unsigned short;
typedef short bf16x8 __attribute__((ext_vector_type(8)));
typedef float f32x4  __attribute__((ext_vector_type(4)));
typedef u16   u16x8  __attribute__((ext_vector_type(8)));
typedef u16   u16x4  __attribute__((ext_vector_type(4)));

__device__ __forceinline__ u16 f2b(float f){
  unsigned u = __float_as_uint(f);
  return (u16)((u + 0x7fffu + ((u >> 16) & 1u)) >> 16);  // RNE
}
__device__ __forceinline__ float b2f(u16 v){
  return __uint_as_float(((unsigned)v) << 16);
}

#define GLOAD16(g, l) __builtin_amdgcn_global_load_lds( \
    (const __attribute__((address_space(1))) unsigned int*)(g), \
    (__attribute__((address_space(3))) unsigned int*)(l), 16, 0, 0)

// ---------------------------------------------------------------------------
// Weight preconvert fp32 -> bf16 (k-contiguous rows, stacked):
//   wT elems: [0,65536) Wk | [65536,131072) Wv | [131072,196608) Wq |
//             [196608,327680) W1 | [327680,458752) W2
// ---------------------------------------------------------------------------
__global__ __launch_bounds__(256) void cvtW_k(
    const float* __restrict__ Wk, const float* __restrict__ Wv,
    const float* __restrict__ Wq, const float* __restrict__ W1,
    const float* __restrict__ W2, u16* __restrict__ wT)
{
  long e = ((long)blockIdx.x * 256 + threadIdx.x) * 8;
  const float* src; long off;
  if      (e < 65536)  { src = Wk; off = e; }
  else if (e < 131072) { src = Wv; off = e - 65536; }
  else if (e < 196608) { src = Wq; off = e - 131072; }
  else if (e < 327680) { src = W1; off = e - 196608; }
  else                 { src = W2; off = e - 327680; }
  float4 f0 = *reinterpret_cast<const float4*>(src + off);
  float4 f1 = *reinterpret_cast<const float4*>(src + off + 4);
  u16x8 p;
  p[0]=f2b(f0.x); p[1]=f2b(f0.y); p[2]=f2b(f0.z); p[3]=f2b(f0.w);
  p[4]=f2b(f1.x); p[5]=f2b(f1.y); p[6]=f2b(f1.z); p[7]=f2b(f1.w);
  *reinterpret_cast<u16x8*>(wT + e) = p;
}

// bias stack [bk;bv] + zero BN stat accumulators
__global__ void prep_k(const float* __restrict__ bk, const float* __restrict__ bv,
                       float* __restrict__ bKV, float* __restrict__ stats)
{
  int i = blockIdx.x * 256 + threadIdx.x;       // grid 6*256 = 1536
  if (i < 512)       bKV[i] = (i < 256) ? bk[i] : bv[i - 256];
  else               stats[i - 512] = 0.f;      // 1024 floats: sum, sumsq
}

// ---------------------------------------------------------------------------
// Transpose+convert: in fp32 [B][256][NCtot] -> out bf16 [B][NCtot][256].
// ---------------------------------------------------------------------------
__global__ __launch_bounds__(256) void transpose_k(
    const float* __restrict__ in, u16* __restrict__ out,
    int NCtot, long outBatch)
{
  __shared__ u16 sT[64][264];
  const int t = threadIdx.x, b = blockIdx.y;
  const int nr0 = blockIdx.x * 64;
  const int cb = t >> 2, nrq = t & 3;
  const long ib = (long)b * 256 * NCtot + nr0;

  #pragma unroll
  for (int ci = 0; ci < 4; ++ci){
    const int c = cb + ci * 64;
    const float* src = in + ib + (long)c * NCtot + nrq * 16;
    #pragma unroll
    for (int j = 0; j < 4; ++j){
      float4 f = *reinterpret_cast<const float4*>(src + j * 4);
      int nr = nrq * 16 + j * 4;
      sT[nr+0][c] = f2b(f.x); sT[nr+1][c] = f2b(f.y);
      sT[nr+2][c] = f2b(f.z); sT[nr+3][c] = f2b(f.w);
    }
  }
  __syncthreads();
  const int row = t >> 2, qtr = t & 3;
  u16* orow = out + (long)b * outBatch + (long)(nr0 + row) * 256 + qtr * 64;
  #pragma unroll
  for (int i = 0; i < 8; ++i)
    *reinterpret_cast<u16x8*>(orow + i * 8) =
        *reinterpret_cast<const u16x8*>(&sT[row][qtr * 64 + i * 8]);
}

// ---------------------------------------------------------------------------
// GEMM: C[rows x NCH] = A[rows x KD] (bf16 k-contig) * Wb[NCH x KD]^T + bias.
// Both operands via global_load_lds (pre-swizzled source, XOR-swizzled reads),
// 2-phase double-buffered. 128x128 tile, BK=64, 4 waves, 16x16x32 bf16 MFMA.
// MODE 0: bf16 C. MODE 1: + per-ch sum/sumsq atomics.
// MODE 2: out = relu(acc + bias + residT[row][ch]) -> fp32 outF [ch][row].
// ---------------------------------------------------------------------------
template<int MODE, int KD>
__global__ __launch_bounds__(256) void gemm_k(
    const u16* __restrict__ A, long aBatch, int chTiles,
    const u16* __restrict__ Wb, const float* __restrict__ bias,
    u16* __restrict__ outH, long oBatch, int NCH,
    float* __restrict__ statSum, float* __restrict__ statSq,
    const u16* __restrict__ residT,
    float* __restrict__ outF, long fBatch)
{
  __shared__ __align__(16) char sA[2][16384];  // [128 rows][64 k] bf16 (swz)
  __shared__ __align__(16) char sB[2][16384];  // [128 ch  ][64 k] bf16 (swz)

  const int t = threadIdx.x, lane = t & 63, wid = t >> 6;
  const int wm = wid >> 1, wn = wid & 1;
  const int b = blockIdx.z;

  // XCD-aware bijective swizzle (ch-tile inner)
  const int nwg = gridDim.x, orig = blockIdx.x;
  const int qq = nwg >> 3, rr = nwg & 7, xcd = orig & 7, pos = orig >> 3;
  const int wg = (xcd < rr ? xcd * (qq + 1) : rr * (qq + 1) + (xcd - rr) * qq) + pos;
  const int rowT = wg / chTiles, chT = wg % chTiles;

  const u16* Ab = A + (long)b * aBatch + (long)rowT * 128 * KD;
  const u16* Wt = Wb + (long)chT * 128 * KD;
  const int sub = lane >> 3, kc8 = ((lane & 7) ^ sub) * 8;  // source pre-swizzle

  f32x4 acc[4][4];
  #pragma unroll
  for (int i = 0; i < 4; ++i)
    #pragma unroll
    for (int j = 0; j < 4; ++j) acc[i][j] = (f32x4){0.f,0.f,0.f,0.f};

  auto STAGE = [&](int buf, int ks){
    const int k0 = ks * 64;
    #pragma unroll
    for (int i = 0; i < 4; ++i){
      const int chunk = wid * 4 + i;
      GLOAD16(Ab + (long)(chunk*8 + sub)*KD + k0 + kc8, sA[buf] + chunk*1024);
      GLOAD16(Wt + (long)(chunk*8 + sub)*KD + k0 + kc8, sB[buf] + chunk*1024);
    }
  };

  constexpr int NT = KD / 64;
  STAGE(0, 0);
  __syncthreads();
  int cur = 0;
  for (int ks = 0; ks < NT; ++ks){
    if (ks + 1 < NT) STAGE(cur ^ 1, ks + 1);
    const char* pA = sA[cur]; const char* pB = sB[cur];
    #pragma unroll
    for (int kk = 0; kk < 2; ++kk){
      bf16x8 af[4], bf[4];
      #pragma unroll
      for (int mi = 0; mi < 4; ++mi){
        int m = wm*64 + mi*16 + (lane & 15);
        af[mi] = *reinterpret_cast<const bf16x8*>(
            pA + ((m*128 + kk*64 + (lane>>4)*16) ^ ((m & 7) << 4)));
      }
      #pragma unroll
      for (int ni = 0; ni < 4; ++ni){
        int c = wn*64 + ni*16 + (lane & 15);
        bf[ni] = *reinterpret_cast<const bf16x8*>(
            pB + ((c*128 + kk*64 + (lane>>4)*16) ^ ((c & 7) << 4)));
      }
      #pragma unroll
      for (int mi = 0; mi < 4; ++mi)
        #pragma unroll
        for (int ni = 0; ni < 4; ++ni)
          acc[mi][ni] = __builtin_amdgcn_mfma_f32_16x16x32_bf16(
              af[mi], bf[ni], acc[mi][ni], 0, 0, 0);
    }
    __syncthreads();
    cur ^= 1;
  }

  // ---- epilogue (C/D: col = lane&15, row = (lane>>4)*4 + j)
  int chI[4]; float bv[4];
  #pragma unroll
  for (int ni = 0; ni < 4; ++ni){
    int ch = chT*128 + wn*64 + ni*16 + (lane & 15);
    chI[ni] = ch;
    bv[ni] = bias[ch];
  }
  if (MODE <= 1){
    float s[4] = {0,0,0,0}, sq[4] = {0,0,0,0};
    u16* outb = outH + (long)b * oBatch;
    #pragma unroll
    for (int mi = 0; mi < 4; ++mi){
      #pragma unroll
      for (int j = 0; j < 4; ++j){
        const long row = rowT*128 + wm*64 + mi*16 + (lane>>4)*4 + j;
        #pragma unroll
        for (int ni = 0; ni < 4; ++ni){
          float v = acc[mi][ni][j] + bv[ni];
          outb[row * NCH + chI[ni]] = f2b(v);
          if (MODE == 1){ s[ni] += v; sq[ni] += v * v; }
        }
      }
    }
    if (MODE == 1){
      #pragma unroll
      for (int ni = 0; ni < 4; ++ni){
        s[ni]  += __shfl_xor(s[ni], 16);  s[ni]  += __shfl_xor(s[ni], 32);
        sq[ni] += __shfl_xor(sq[ni], 16); sq[ni] += __shfl_xor(sq[ni], 32);
      }
      if (lane < 16){
        #pragma unroll
        for (int ni = 0; ni < 4; ++ni){
          atomicAdd(&statSum[chI[ni]], s[ni]);
          atomicAdd(&statSq[chI[ni]],  sq[ni]);
        }
      }
    }
  } else {
    const u16* rb = residT + (long)b * ((long)NRQ * 256);
    #pragma unroll
    for (int mi = 0; mi < 4; ++mi){
      const int nr0 = rowT*128 + wm*64 + mi*16 + (lane>>4)*4;
      #pragma unroll
      for (int ni = 0; ni < 4; ++ni){
        float4 o;
        o.x = fmaxf(acc[mi][ni][0] + bv[ni] + b2f(rb[(long)(nr0+0)*256 + chI[ni]]), 0.f);
        o.y = fmaxf(acc[mi][ni][1] + bv[ni] + b2f(rb[(long)(nr0+1)*256 + chI[ni]]), 0.f);
        o.z = fmaxf(acc[mi][ni][2] + bv[ni] + b2f(rb[(long)(nr0+2)*256 + chI[ni]]), 0.f);
        o.w = fmaxf(acc[mi][ni][3] + bv[ni] + b2f(rb[(long)(nr0+3)*256 + chI[ni]]), 0.f);
        *reinterpret_cast<float4*>(outF + (long)b*fBatch + (long)chI[ni]*NRQ + nr0) = o;
      }
    }
  }
}

// ---------------------------------------------------------------------------
// Fused kv-projection + attention. Block = 512 thr (8 waves), 8 points
// (128 feat rows) x 512 kv-channels. GEMM: C = fT_tile[128x256] @ wKV^T,
// A resident in LDS (staged once), W staged per BK=64 step (single buffer).
// k,v never touch HBM: C -> LDS (pitch 1040B), then per-point attention
// (wave = point): logits+softmax (lane=(h,kk)) and PV (lane=ch-group),
// + queries residual, write aggT bf16.
// ---------------------------------------------------------------------------
__global__ __launch_bounds__(512, 2) void kvattn_k(
    const u16* __restrict__ fT, const u16* __restrict__ wKV,
    const float* __restrict__ bKV, const u16* __restrict__ qT,
    const float* __restrict__ queries, u16* __restrict__ aggT)
{
  __shared__ __align__(16) char LDS[141312];
  char* sA  = LDS;                    // 64KB: [128 r][32 16B-slots, swz ^(r&7)]
  char* sW  = LDS + 65536;            // 64KB: [512 ch][8 16B-slots, swz ^(ch&7)]
  char* sKV = LDS;                    // attn: [128 r][520 ch u16] pitch 1040B
  float* sS = (float*)(LDS + 133120); // [8 p][4 h][16 kk][4 r]

  const int t = threadIdx.x, lane = t & 63, wid = t >> 6;
  const int wr = wid >> 2, wc = wid & 3;         // 2 x 4 waves
  const int b = blockIdx.y;
  const long row0 = (long)blockIdx.x * 128;
  const u16* Ab = fT + ((long)b * NKF + row0) * 256;

  // ---- stage A once (64 chunks of 1KB; chunk = 2 rows x 32 slots)
  #pragma unroll
  for (int i = 0; i < 8; ++i){
    const int c = wid*8 + i;
    const int r = 2*c + (lane >> 5);
    GLOAD16(Ab + (long)r*256 + (((lane & 31) ^ (r & 7)) * 8), sA + c*1024);
  }
  // ---- stage W step 0 (64 chunks; chunk = 8 ch x 8 slots)
  {
    #pragma unroll
    for (int i = 0; i < 8; ++i){
      const int c = wid*8 + i;
      const int ch = c*8 + (lane >> 3);
      GLOAD16(wKV + (long)ch*256 + (((lane & 7) ^ (ch & 7)) * 8), sW + c*1024);
    }
  }
  __syncthreads();

  f32x4 acc[4][8];
  #pragma unroll
  for (int i = 0; i < 4; ++i)
    #pragma unroll
    for (int j = 0; j < 8; ++j) acc[i][j] = (f32x4){0.f,0.f,0.f,0.f};

  for (int ks = 0; ks < 4; ++ks){
    #pragma unroll
    for (int kk = 0; kk < 2; ++kk){
      bf16x8 af[4];
      #pragma unroll
      for (int mi = 0; mi < 4; ++mi){
        const int m = wr*64 + mi*16 + (lane & 15);
        const int j = ks*8 + kk*4 + (lane >> 4);
        af[mi] = *reinterpret_cast<const bf16x8*>(sA + m*512 + ((j ^ (m & 7))*16));
      }
      #pragma unroll
      for (int ni = 0; ni < 8; ++ni){
        const int ch = wc*128 + ni*16 + (lane & 15);
        const int j2 = kk*4 + (lane >> 4);
        bf16x8 bf = *reinterpret_cast<const bf16x8*>(sW + ch*128 + ((j2 ^ (ch & 7))*16));
        #pragma unroll
        for (int mi = 0; mi < 4; ++mi)
          acc[mi][ni] = __builtin_amdgcn_mfma_f32_16x16x32_bf16(
              af[mi], bf, acc[mi][ni], 0, 0, 0);
      }
    }
    __syncthreads();                  // all reads of sW done
    if (ks < 3){
      #pragma unroll
      for (int i = 0; i < 8; ++i){
        const int c = wid*8 + i;
        const int ch = c*8 + (lane >> 3);
        GLOAD16(wKV + (long)ch*256 + (ks+1)*64 + (((lane & 7) ^ (ch & 7)) * 8),
                sW + c*1024);
      }
      __syncthreads();
    }
  }

  // ---- C (+bias) -> sKV  (k: ch 0-255, v: ch 256-511)
  float bv[8];
  #pragma unroll
  for (int ni = 0; ni < 8; ++ni) bv[ni] = bKV[wc*128 + ni*16 + (lane & 15)];
  #pragma unroll
  for (int mi = 0; mi < 4; ++mi){
    #pragma unroll
    for (int ni = 0; ni < 8; ++ni){
      const int ch = wc*128 + ni*16 + (lane & 15);
      #pragma unroll
      for (int j = 0; j < 4; ++j){
        const int r = wr*64 + mi*16 + (lane>>4)*4 + j;
        *reinterpret_cast<u16*>(sKV + r*1040 + ch*2) = f2b(acc[mi][ni][j] + bv[ni]);
      }
    }
  }
  __syncthreads();

  // ---- phase A: logits + softmax. wave = point; lane = (h, kk)
  const int p = wid;
  const int nq = (int)(row0 >> 4) + p;          // global point index
  {
    const int h = (lane >> 4) & 3, kk = lane & 15;
    const u16* qb = qT + ((long)b*NRQ + (long)nq*4)*256 + h*64;
    const char* kr = sKV + (p*16 + kk)*1040 + h*128;
    float l[4] = {0.f,0.f,0.f,0.f};
    #pragma unroll
    for (int d8 = 0; d8 < 8; ++d8){
      u16x8 kw = *reinterpret_cast<const u16x8*>(kr + d8*16);
      float kf[8];
      #pragma unroll
      for (int e = 0; e < 8; ++e) kf[e] = b2f(kw[e]);
      #pragma unroll
      for (int r = 0; r < 4; ++r){
        u16x8 qw = *reinterpret_cast<const u16x8*>(qb + r*256 + d8*8);
        #pragma unroll
        for (int e = 0; e < 8; ++e) l[r] = fmaf(kf[e], b2f(qw[e]), l[r]);
      }
    }
    float4 prob;
    #pragma unroll
    for (int r = 0; r < 4; ++r){
      float x = l[r] * 0.125f;
      float m = x;
      #pragma unroll
      for (int off = 1; off < 16; off <<= 1) m = fmaxf(m, __shfl_xor(m, off));
      float e = __expf(x - m);
      float ssum = e;
      #pragma unroll
      for (int off = 1; off < 16; off <<= 1) ssum += __shfl_xor(ssum, off);
      float pr = e / ssum;
      if (r == 0) prob.x = pr; else if (r == 1) prob.y = pr;
      else if (r == 2) prob.z = pr; else prob.w = pr;
    }
    *reinterpret_cast<float4*>(sS + (((p*4 + h)*16 + kk)*4)) = prob;
  }
  __syncthreads();   // safety: order sS writes vs cross-lane reads below

  // ---- phase B: agg = v @ soft^T + queries residual. lane = 4-ch group
  {
    const int ch0 = lane * 4, h = lane >> 4;
    const char* vb = sKV + (p*16)*1040 + 512 + lane*8;
    const float* ss = sS + (p*4 + h)*64;
    float a[4][4] = {};                          // [r][cc]
    #pragma unroll
    for (int kk = 0; kk < 16; ++kk){
      u16x4 vv = *reinterpret_cast<const u16x4*>(vb + kk*1040);
      float4 sv = *reinterpret_cast<const float4*>(ss + kk*4);
      #pragma unroll
      for (int cc = 0; cc < 4; ++cc){
        float vf = b2f(vv[cc]);
        a[0][cc] += sv.x*vf; a[1][cc] += sv.y*vf;
        a[2][cc] += sv.z*vf; a[3][cc] += sv.w*vf;
      }
    }
    float qv[4][4];                              // [cc][r]
    #pragma unroll
    for (int cc = 0; cc < 4; ++cc){
      float4 q4 = *reinterpret_cast<const float4*>(
          queries + ((long)b*256 + ch0 + cc) * NRQ + (long)nq * 4);
      qv[cc][0]=q4.x; qv[cc][1]=q4.y; qv[cc][2]=q4.z; qv[cc][3]=q4.w;
    }
    #pragma unroll
    for (int r = 0; r < 4; ++r){
      u16x4 pk;
      #pragma unroll
      for (int cc = 0; cc < 4; ++cc) pk[cc] = f2b(a[r][cc] + qv[cc][r]);
      *reinterpret_cast<u16x4*>(aggT + ((long)b*NRQ + (long)nq*4 + r)*256 + ch0) = pk;
    }
  }
}

// ---------------------------------------------------------------------------
__global__ void bnrelu_k(u16* __restrict__ h1, const float* __restrict__ sc,
                         const float* __restrict__ sh)
{
  const long total = (long)NB * NRQ * 512 / 8;
  for (long i = (long)blockIdx.x * blockDim.x + threadIdx.x; i < total;
       i += (long)gridDim.x * blockDim.x){
    u16x8 v = *reinterpret_cast<const u16x8*>(h1 + i * 8);
    int chb = (int)((i * 8) & 511);
    float4 s0 = *reinterpret_cast<const float4*>(sc + chb);
    float4 s1 = *reinterpret_cast<const float4*>(sc + chb + 4);
    float4 h0 = *reinterpret_cast<const float4*>(sh + chb);
    float4 h1v= *reinterpret_cast<const float4*>(sh + chb + 4);
    u16x8 o;
    o[0]=f2b(fmaxf(b2f(v[0])*s0.x+h0.x ,0.f)); o[1]=f2b(fmaxf(b2f(v[1])*s0.y+h0.y ,0.f));
    o[2]=f2b(fmaxf(b2f(v[2])*s0.z+h0.z ,0.f)); o[3]=f2b(fmaxf(b2f(v[3])*s0.w+h0.w ,0.f));
    o[4]=f2b(fmaxf(b2f(v[4])*s1.x+h1v.x,0.f)); o[5]=f2b(fmaxf(b2f(v[5])*s1.y+h1v.y,0.f));
    o[6]=f2b(fmaxf(b2f(v[6])*s1.z+h1v.z,0.f)); o[7]=f2b(fmaxf(b2f(v[7])*s1.w+h1v.w,0.f));
    *reinterpret_cast<u16x8*>(h1 + i * 8) = o;
  }
}

__global__ void finalize_k(const float* __restrict__ st,
                           const float* __restrict__ gamma,
                           const float* __restrict__ beta,
                           float* __restrict__ out)   // scale[512], shift[512]
{
  int o = blockIdx.x*256 + threadIdx.x;
  const float inv = 1.f / 131072.f;                   // B*N*R
  float mean = st[o] * inv;
  float var  = st[512 + o] * inv - mean*mean;
  float sc   = gamma[o] * rsqrtf(var + 1e-5f);
  out[o]       = sc;
  out[512 + o] = beta[o] - mean * sc;
}

// ---------------------------------------------------------------------------
extern "C" void kernel_launch(void* const* d_in, const int* in_sizes, int n_in,
                              void* d_out, int out_size, void* d_ws, size_t ws_size,
                              hipStream_t stream)
{
  (void)in_sizes; (void)n_in; (void)out_size; (void)ws_size;
  const float* queries = (const float*)d_in[0];
  const float* feats   = (const float*)d_in[1];
  const float* Wq = (const float*)d_in[2];
  const float* bq = (const float*)d_in[3];
  const float* Wk = (const float*)d_in[4];
  const float* bk = (const float*)d_in[5];
  const float* Wv = (const float*)d_in[6];
  const float* bv = (const float*)d_in[7];
  const float* W1 = (const float*)d_in[8];
  const float* b1 = (const float*)d_in[9];
  const float* gamma = (const float*)d_in[10];
  const float* beta  = (const float*)d_in[11];
  const float* W2 = (const float*)d_in[12];
  const float* b2 = (const float*)d_in[13];

  // ws layout (bytes):
  //   [0, 268.4M)        : fT bf16 [B][NKF][256]; h1T (134.2M) aliases after
  //   [268.4M, 335.5M)   : qrT (dead after q-GEMM) -> aggT bf16 [B][NRQ][256]
  //   [335.5M, 402.7M)   : qT bf16 [B][NRQ][256]
  //   [402.7M, +8K)      : stats (sum512, sq512, scale512, shift512)
  //   [402.7M+8K, +920K) : wT bf16 weights + bKV fp32
  char* ws = (char*)d_ws;
  u16*   fT    = (u16*)ws;
  u16*   h1T   = (u16*)ws;
  u16*   qrT   = (u16*)(ws + 268435456L);
  u16*   aggT  = (u16*)(ws + 268435456L);
  u16*   qT    = (u16*)(ws + 335544320L);
  float* stats = (float*)(ws + 402653184L);
  float* scale = stats + 1024;
  float* shift = stats + 1536;
  u16*   wT    = (u16*)(ws + 402661376L);
  u16*   wKV   = wT;                 // 512 x 256
  u16*   wQ    = wT + 131072;        // 256 x 256
  u16*   wW1   = wT + 196608;        // 512 x 256
  u16*   wW2   = wT + 327680;        // 256 x 512
  float* bKV   = (float*)(wT + 458752);

  cvtW_k<<<dim3(224), 256, 0, stream>>>(Wk, Wv, Wq, W1, W2, wT);
  prep_k<<<dim3(6), 256, 0, stream>>>(bk, bv, bKV, stats);

  // queries -> qrT bf16 [B][NRQ][256]
  transpose_k<<<dim3(NRQ/64, NB), 256, 0, stream>>>(queries, qrT, NRQ, (long)NRQ*256);

  // qT = qrT @ Wq^T + bq
  gemm_k<0, 256><<<dim3(512, 1, NB), 256, 0, stream>>>(
      qrT, (long)NRQ*256, 2, wQ, bq,
      qT, (long)NRQ*256, 256, nullptr, nullptr, nullptr, nullptr, 0);

  // feats -> fT bf16 [B][NKF][256]
  transpose_k<<<dim3(NKF/64, NB), 256, 0, stream>>>(feats, fT, NKF, (long)NKF*256);

  // fused kv-proj + attention -> aggT
  kvattn_k<<<dim3(NKF/128, NB), 512, 0, stream>>>(fT, wKV, bKV, qT, queries, aggT);

  // h1 = aggT @ W1^T + b1 -> bf16 + BN stats
  gemm_k<1, 256><<<dim3(1024, 1, NB), 256, 0, stream>>>(
      aggT, (long)NRQ*256, 4, wW1, b1,
      h1T, (long)NRQ*512, 512, stats, stats + 512, nullptr, nullptr, 0);

  finalize_k<<<dim3(2), 256, 0, stream>>>(stats, gamma, beta, scale);

  // h1 <- relu(bn(h1)) in place
  bnrelu_k<<<dim3(2048), 256, 0, stream>>>(h1T, scale, shift);

  // d_out = relu(h1' @ W2^T + b2 + aggT) -> fp32 [B][256][NRQ]
  gemm_k<2, 512><<<dim3(512, 1, NB), 256, 0, stream>>>(
      h1T, (long)NRQ*512, 2, wW2, b2,
      nullptr, 0, 256, nullptr, nullptr, aggT, (float*)d_out, (long)256*NRQ);
}

// Round 6
// 826.362 us; speedup vs baseline: 1.8724x; 1.0057x over previous
//
#include <hip/hip_runtime.h>
#include <hip/hip_bf16.h>

#define NB 4
#define NRQ 32768      // per-batch q-side rows  (n*4)
#define NKF 131072     // per-batch feats rows   (n*16)

using u16 = unsigned short;
typedef short bf16x8 __attribute__((ext_vector_type(8)));
typedef float f32x4  __attribute__((ext_vector_type(4)));
typedef u16   u16x8  __attribute__((ext_vector_type(8)));
typedef u16   u16x4  __attribute__((ext_vector_type(4)));
typedef u16   u16x2  __attribute__((ext_vector_type(2)));

__device__ __forceinline__ u16 f2b(float f){
  unsigned u = __float_as_uint(f);
  return (u16)((u + 0x7fffu + ((u >> 16) & 1u)) >> 16);  // RNE
}
__device__ __forceinline__ float b2f(u16 v){
  return __uint_as_float(((unsigned)v) << 16);
}

#define GLOAD16(g, l) __builtin_amdgcn_global_load_lds( \
    (const __attribute__((address_space(1))) unsigned int*)(g), \
    (__attribute__((address_space(3))) unsigned int*)(l), 16, 0, 0)

// ---------------------------------------------------------------------------
// Weight preconvert fp32 -> bf16 (k-contiguous rows, stacked):
//   wT elems: [0,65536) Wk | [65536,131072) Wv | [131072,196608) Wq |
//             [196608,327680) W1 | [327680,458752) W2
// ---------------------------------------------------------------------------
__global__ __launch_bounds__(256) void cvtW_k(
    const float* __restrict__ Wk, const float* __restrict__ Wv,
    const float* __restrict__ Wq, const float* __restrict__ W1,
    const float* __restrict__ W2, u16* __restrict__ wT)
{
  long e = ((long)blockIdx.x * 256 + threadIdx.x) * 8;
  const float* src; long off;
  if      (e < 65536)  { src = Wk; off = e; }
  else if (e < 131072) { src = Wv; off = e - 65536; }
  else if (e < 196608) { src = Wq; off = e - 131072; }
  else if (e < 327680) { src = W1; off = e - 196608; }
  else                 { src = W2; off = e - 327680; }
  float4 f0 = *reinterpret_cast<const float4*>(src + off);
  float4 f1 = *reinterpret_cast<const float4*>(src + off + 4);
  u16x8 p;
  p[0]=f2b(f0.x); p[1]=f2b(f0.y); p[2]=f2b(f0.z); p[3]=f2b(f0.w);
  p[4]=f2b(f1.x); p[5]=f2b(f1.y); p[6]=f2b(f1.z); p[7]=f2b(f1.w);
  *reinterpret_cast<u16x8*>(wT + e) = p;
}

// bias stack [bk;bv] + zero BN stat accumulators
__global__ void prep_k(const float* __restrict__ bk, const float* __restrict__ bv,
                       float* __restrict__ bKV, float* __restrict__ stats)
{
  int i = blockIdx.x * 256 + threadIdx.x;       // grid 6*256 = 1536
  if (i < 512)       bKV[i] = (i < 256) ? bk[i] : bv[i - 256];
  else               stats[i - 512] = 0.f;      // 1024 floats: sum, sumsq
}

// ---------------------------------------------------------------------------
// Transpose+convert: in fp32 [B][256][NCtot] -> out bf16 [B][NCtot][256].
// ---------------------------------------------------------------------------
__global__ __launch_bounds__(256) void transpose_k(
    const float* __restrict__ in, u16* __restrict__ out,
    int NCtot, long outBatch)
{
  __shared__ u16 sT[64][264];
  const int t = threadIdx.x, b = blockIdx.y;
  const int nr0 = blockIdx.x * 64;
  const int cb = t >> 2, nrq = t & 3;
  const long ib = (long)b * 256 * NCtot + nr0;

  #pragma unroll
  for (int ci = 0; ci < 4; ++ci){
    const int c = cb + ci * 64;
    const float* src = in + ib + (long)c * NCtot + nrq * 16;
    #pragma unroll
    for (int j = 0; j < 4; ++j){
      float4 f = *reinterpret_cast<const float4*>(src + j * 4);
      int nr = nrq * 16 + j * 4;
      sT[nr+0][c] = f2b(f.x); sT[nr+1][c] = f2b(f.y);
      sT[nr+2][c] = f2b(f.z); sT[nr+3][c] = f2b(f.w);
    }
  }
  __syncthreads();
  const int row = t >> 2, qtr = t & 3;
  u16* orow = out + (long)b * outBatch + (long)(nr0 + row) * 256 + qtr * 64;
  #pragma unroll
  for (int i = 0; i < 8; ++i)
    *reinterpret_cast<u16x8*>(orow + i * 8) =
        *reinterpret_cast<const u16x8*>(&sT[row][qtr * 64 + i * 8]);
}

// ---------------------------------------------------------------------------
// GEMM: C[rows x NCH] = A[rows x KD] (bf16 k-contig) * Wb[NCH x KD]^T + bias.
// Both operands via global_load_lds (pre-swizzled source, XOR-swizzled reads),
// 2-phase double-buffered. 128x128 tile, BK=64, 4 waves, 16x16x32 bf16 MFMA.
// MODE 0: bf16 C. MODE 1: + per-ch sum/sumsq atomics.
// MODE 2: out = relu(acc + bias + residT[row][ch]) -> fp32 outF [ch][row].
// ---------------------------------------------------------------------------
template<int MODE, int KD>
__global__ __launch_bounds__(256) void gemm_k(
    const u16* __restrict__ A, long aBatch, int chTiles,
    const u16* __restrict__ Wb, const float* __restrict__ bias,
    u16* __restrict__ outH, long oBatch, int NCH,
    float* __restrict__ statSum, float* __restrict__ statSq,
    const u16* __restrict__ residT,
    float* __restrict__ outF, long fBatch)
{
  __shared__ __align__(16) char sA[2][16384];  // [128 rows][64 k] bf16 (swz)
  __shared__ __align__(16) char sB[2][16384];  // [128 ch  ][64 k] bf16 (swz)

  const int t = threadIdx.x, lane = t & 63, wid = t >> 6;
  const int wm = wid >> 1, wn = wid & 1;
  const int b = blockIdx.z;

  // XCD-aware bijective swizzle (ch-tile inner)
  const int nwg = gridDim.x, orig = blockIdx.x;
  const int qq = nwg >> 3, rr = nwg & 7, xcd = orig & 7, pos = orig >> 3;
  const int wg = (xcd < rr ? xcd * (qq + 1) : rr * (qq + 1) + (xcd - rr) * qq) + pos;
  const int rowT = wg / chTiles, chT = wg % chTiles;

  const u16* Ab = A + (long)b * aBatch + (long)rowT * 128 * KD;
  const u16* Wt = Wb + (long)chT * 128 * KD;
  const int sub = lane >> 3, kc8 = ((lane & 7) ^ sub) * 8;  // source pre-swizzle

  f32x4 acc[4][4];
  #pragma unroll
  for (int i = 0; i < 4; ++i)
    #pragma unroll
    for (int j = 0; j < 4; ++j) acc[i][j] = (f32x4){0.f,0.f,0.f,0.f};

  auto STAGE = [&](int buf, int ks){
    const int k0 = ks * 64;
    #pragma unroll
    for (int i = 0; i < 4; ++i){
      const int chunk = wid * 4 + i;
      GLOAD16(Ab + (long)(chunk*8 + sub)*KD + k0 + kc8, sA[buf] + chunk*1024);
      GLOAD16(Wt + (long)(chunk*8 + sub)*KD + k0 + kc8, sB[buf] + chunk*1024);
    }
  };

  constexpr int NT = KD / 64;
  STAGE(0, 0);
  __syncthreads();
  int cur = 0;
  for (int ks = 0; ks < NT; ++ks){
    if (ks + 1 < NT) STAGE(cur ^ 1, ks + 1);
    const char* pA = sA[cur]; const char* pB = sB[cur];
    #pragma unroll
    for (int kk = 0; kk < 2; ++kk){
      bf16x8 af[4], bf[4];
      #pragma unroll
      for (int mi = 0; mi < 4; ++mi){
        int m = wm*64 + mi*16 + (lane & 15);
        af[mi] = *reinterpret_cast<const bf16x8*>(
            pA + ((m*128 + kk*64 + (lane>>4)*16) ^ ((m & 7) << 4)));
      }
      #pragma unroll
      for (int ni = 0; ni < 4; ++ni){
        int c = wn*64 + ni*16 + (lane & 15);
        bf[ni] = *reinterpret_cast<const bf16x8*>(
            pB + ((c*128 + kk*64 + (lane>>4)*16) ^ ((c & 7) << 4)));
      }
      #pragma unroll
      for (int mi = 0; mi < 4; ++mi)
        #pragma unroll
        for (int ni = 0; ni < 4; ++ni)
          acc[mi][ni] = __builtin_amdgcn_mfma_f32_16x16x32_bf16(
              af[mi], bf[ni], acc[mi][ni], 0, 0, 0);
    }
    __syncthreads();
    cur ^= 1;
  }

  // ---- epilogue (C/D: col = lane&15, row = (lane>>4)*4 + j)
  int chI[4]; float bv[4];
  #pragma unroll
  for (int ni = 0; ni < 4; ++ni){
    int ch = chT*128 + wn*64 + ni*16 + (lane & 15);
    chI[ni] = ch;
    bv[ni] = bias[ch];
  }
  if (MODE <= 1){
    float s[4] = {0,0,0,0}, sq[4] = {0,0,0,0};
    u16* outb = outH + (long)b * oBatch;
    #pragma unroll
    for (int mi = 0; mi < 4; ++mi){
      #pragma unroll
      for (int j = 0; j < 4; ++j){
        const long row = rowT*128 + wm*64 + mi*16 + (lane>>4)*4 + j;
        #pragma unroll
        for (int ni = 0; ni < 4; ++ni){
          float v = acc[mi][ni][j] + bv[ni];
          outb[row * NCH + chI[ni]] = f2b(v);
          if (MODE == 1){ s[ni] += v; sq[ni] += v * v; }
        }
      }
    }
    if (MODE == 1){
      #pragma unroll
      for (int ni = 0; ni < 4; ++ni){
        s[ni]  += __shfl_xor(s[ni], 16);  s[ni]  += __shfl_xor(s[ni], 32);
        sq[ni] += __shfl_xor(sq[ni], 16); sq[ni] += __shfl_xor(sq[ni], 32);
      }
      if (lane < 16){
        #pragma unroll
        for (int ni = 0; ni < 4; ++ni){
          atomicAdd(&statSum[chI[ni]], s[ni]);
          atomicAdd(&statSq[chI[ni]],  sq[ni]);
        }
      }
    }
  } else {
    const u16* rb = residT + (long)b * ((long)NRQ * 256);
    #pragma unroll
    for (int mi = 0; mi < 4; ++mi){
      const int nr0 = rowT*128 + wm*64 + mi*16 + (lane>>4)*4;
      #pragma unroll
      for (int ni = 0; ni < 4; ++ni){
        float4 o;
        o.x = fmaxf(acc[mi][ni][0] + bv[ni] + b2f(rb[(long)(nr0+0)*256 + chI[ni]]), 0.f);
        o.y = fmaxf(acc[mi][ni][1] + bv[ni] + b2f(rb[(long)(nr0+1)*256 + chI[ni]]), 0.f);
        o.z = fmaxf(acc[mi][ni][2] + bv[ni] + b2f(rb[(long)(nr0+2)*256 + chI[ni]]), 0.f);
        o.w = fmaxf(acc[mi][ni][3] + bv[ni] + b2f(rb[(long)(nr0+3)*256 + chI[ni]]), 0.f);
        *reinterpret_cast<float4*>(outF + (long)b*fBatch + (long)chI[ni]*NRQ + nr0) = o;
      }
    }
  }
}

// ---------------------------------------------------------------------------
// Fused kv-projection + attention, v2 (2 blocks/CU).
// Block = 512 thr (8 waves), 64 feat rows (4 points) x 512 kv-channels.
// GEMM: BK=32, A and W double-buffered via global_load_lds (1 barrier/step).
// k,v -> LDS only (XOR-swizzled rows). Attention: 2 waves per point
// (r-pair split in QK^T+softmax, ch-half split in PV). Residual from qrT.
// LDS total 76KB -> 2 blocks/CU for cross-block MFMA/VALU overlap.
// ---------------------------------------------------------------------------
__global__ __launch_bounds__(512, 4) void kvattn_k(
    const u16* __restrict__ fT, const u16* __restrict__ wKV,
    const float* __restrict__ bKV, const u16* __restrict__ qT,
    const u16* __restrict__ qrT, u16* __restrict__ aggT)
{
  __shared__ __align__(16) char LDS[77824];
  char*  sAd = LDS;                    // 2 x 4KB : [64 r][4 slots] swz ^((r>>1)&3)
  char*  sW  = LDS + 8192;             // 2 x 32KB: [512 ch][4 slots] swz ^((ch>>1)&3)
  char*  sKV = LDS;                    // attn: [64 r] pitch 1040B, byte ^((r&7)<<4)
  float* sS  = (float*)(LDS + 73728);  // [4 p][4 h][16 kk][4 r]

  const int t = threadIdx.x, lane = t & 63, wid = t >> 6;
  const int wr = wid >> 2, wc = wid & 3;       // 2 x 4 waves for GEMM
  const int b = blockIdx.y;
  const long row0 = (long)blockIdx.x * 64;
  const u16* Ab = fT + ((long)b * NKF + row0) * 256;

  auto STAGE = [&](int buf, int ks){
    const int k0 = ks * 32;
    #pragma unroll
    for (int i = 0; i < 4; ++i){
      const int cw = wid * 4 + i;                  // 32 W chunks
      const int ch = cw * 16 + (lane >> 2), jd = lane & 3;
      GLOAD16(wKV + (long)ch * 256 + k0 + ((jd ^ ((ch >> 1) & 3)) * 8),
              sW + buf * 32768 + cw * 1024);
    }
    if (wid < 4){                                  // 4 A chunks
      const int r = wid * 16 + (lane >> 2), jd = lane & 3;
      GLOAD16(Ab + (long)r * 256 + k0 + ((jd ^ ((r >> 1) & 3)) * 8),
              sAd + buf * 4096 + wid * 1024);
    }
  };

  f32x4 acc[2][8];
  #pragma unroll
  for (int i = 0; i < 2; ++i)
    #pragma unroll
    for (int j = 0; j < 8; ++j) acc[i][j] = (f32x4){0.f,0.f,0.f,0.f};

  STAGE(0, 0);
  __syncthreads();
  int cur = 0;
  for (int ks = 0; ks < 8; ++ks){
    if (ks < 7) STAGE(cur ^ 1, ks + 1);
    const char* pA = sAd + cur * 4096;
    const char* pW = sW  + cur * 32768;
    bf16x8 af[2];
    #pragma unroll
    for (int mi = 0; mi < 2; ++mi){
      const int m = wr*32 + mi*16 + (lane & 15);
      af[mi] = *reinterpret_cast<const bf16x8*>(
          pA + m*64 + (((lane>>4) ^ ((m>>1)&3)) * 16));
    }
    #pragma unroll
    for (int ni = 0; ni < 8; ++ni){
      const int ch = wc*128 + ni*16 + (lane & 15);
      bf16x8 bf = *reinterpret_cast<const bf16x8*>(
          pW + ch*64 + (((lane>>4) ^ ((ch>>1)&3)) * 16));
      acc[0][ni] = __builtin_amdgcn_mfma_f32_16x16x32_bf16(af[0], bf, acc[0][ni], 0,0,0);
      acc[1][ni] = __builtin_amdgcn_mfma_f32_16x16x32_bf16(af[1], bf, acc[1][ni], 0,0,0);
    }
    __syncthreads();
    cur ^= 1;
  }

  // ---- C (+bias) -> sKV (k: ch 0-255, v: ch 256-511), swizzled rows
  float bv[8];
  #pragma unroll
  for (int ni = 0; ni < 8; ++ni) bv[ni] = bKV[wc*128 + ni*16 + (lane & 15)];
  #pragma unroll
  for (int mi = 0; mi < 2; ++mi){
    #pragma unroll
    for (int ni = 0; ni < 8; ++ni){
      const int ch = wc*128 + ni*16 + (lane & 15);
      #pragma unroll
      for (int j = 0; j < 4; ++j){
        const int r = wr*32 + mi*16 + (lane>>4)*4 + j;
        *reinterpret_cast<u16*>(sKV + r*1040 + ((ch*2) ^ ((r&7)<<4))) =
            f2b(acc[mi][ni][j] + bv[ni]);
      }
    }
  }
  __syncthreads();

  // ---- phase A: logits + softmax. 2 waves/point: wave = (rh, p); lane=(h,kk)
  const int p = wid & 3, rh = wid >> 2;
  const int nq = blockIdx.x*4 + p;
  {
    const int h = (lane >> 4) & 3, kk = lane & 15;
    const u16* qb = qT + ((long)b*NRQ + (long)nq*4 + rh*2)*256 + h*64;
    const char* kr = sKV + (p*16 + kk)*1040;
    float l0 = 0.f, l1 = 0.f;
    #pragma unroll
    for (int d8 = 0; d8 < 8; ++d8){
      u16x8 kw = *reinterpret_cast<const u16x8*>(
          kr + ((h*128 + d8*16) ^ ((kk & 7) << 4)));
      u16x8 q0 = *reinterpret_cast<const u16x8*>(qb + d8*8);
      u16x8 q1 = *reinterpret_cast<const u16x8*>(qb + 256 + d8*8);
      #pragma unroll
      for (int e = 0; e < 8; ++e){
        float kf = b2f(kw[e]);
        l0 = fmaf(kf, b2f(q0[e]), l0);
        l1 = fmaf(kf, b2f(q1[e]), l1);
      }
    }
    float pr[2]; float lv[2] = {l0, l1};
    #pragma unroll
    for (int r = 0; r < 2; ++r){
      float x = lv[r] * 0.125f;
      float m = x;
      #pragma unroll
      for (int off = 1; off < 16; off <<= 1) m = fmaxf(m, __shfl_xor(m, off));
      float e = __expf(x - m);
      float ssum = e;
      #pragma unroll
      for (int off = 1; off < 16; off <<= 1) ssum += __shfl_xor(ssum, off);
      pr[r] = e / ssum;
    }
    *reinterpret_cast<float2*>(sS + ((p*4 + h)*16 + kk)*4 + rh*2) =
        make_float2(pr[0], pr[1]);
  }
  __syncthreads();

  // ---- phase B: agg = v @ soft^T + qrT residual. 2 waves/point (ch halves)
  {
    const int c0 = rh*128 + lane*2;            // 2 output channels per lane
    const int h = c0 >> 6;
    const char* vrow = sKV + (p*16)*1040;
    const float* ss = sS + (p*4 + h)*64;
    float a[4][2] = {};
    #pragma unroll
    for (int kk = 0; kk < 16; ++kk){
      u16x2 vv = *reinterpret_cast<const u16x2*>(
          vrow + kk*1040 + ((512 + c0*2) ^ ((kk & 7) << 4)));
      float v0 = b2f(vv[0]), v1 = b2f(vv[1]);
      float4 sv = *reinterpret_cast<const float4*>(ss + kk*4);
      a[0][0] += sv.x*v0; a[0][1] += sv.x*v1;
      a[1][0] += sv.y*v0; a[1][1] += sv.y*v1;
      a[2][0] += sv.z*v0; a[2][1] += sv.z*v1;
      a[3][0] += sv.w*v0; a[3][1] += sv.w*v1;
    }
    const u16* rq = qrT + ((long)b*NRQ + (long)nq*4)*256 + c0;
    u16* ob = aggT + ((long)b*NRQ + (long)nq*4)*256 + c0;
    #pragma unroll
    for (int r = 0; r < 4; ++r){
      u16x2 q2 = *reinterpret_cast<const u16x2*>(rq + r*256);
      u16x2 pk;
      pk[0] = f2b(a[r][0] + b2f(q2[0]));
      pk[1] = f2b(a[r][1] + b2f(q2[1]));
      *reinterpret_cast<u16x2*>(ob + r*256) = pk;
    }
  }
}

// ---------------------------------------------------------------------------
__global__ void bnrelu_k(u16* __restrict__ h1, const float* __restrict__ sc,
                         const float* __restrict__ sh)
{
  const long total = (long)NB * NRQ * 512 / 8;
  for (long i = (long)blockIdx.x * blockDim.x + threadIdx.x; i < total;
       i += (long)gridDim.x * blockDim.x){
    u16x8 v = *reinterpret_cast<const u16x8*>(h1 + i * 8);
    int chb = (int)((i * 8) & 511);
    float4 s0 = *reinterpret_cast<const float4*>(sc + chb);
    float4 s1 = *reinterpret_cast<const float4*>(sc + chb + 4);
    float4 h0 = *reinterpret_cast<const float4*>(sh + chb);
    float4 h1v= *reinterpret_cast<const float4*>(sh + chb + 4);
    u16x8 o;
    o[0]=f2b(fmaxf(b2f(v[0])*s0.x+h0.x ,0.f)); o[1]=f2b(fmaxf(b2f(v[1])*s0.y+h0.y ,0.f));
    o[2]=f2b(fmaxf(b2f(v[2])*s0.z+h0.z ,0.f)); o[3]=f2b(fmaxf(b2f(v[3])*s0.w+h0.w ,0.f));
    o[4]=f2b(fmaxf(b2f(v[4])*s1.x+h1v.x,0.f)); o[5]=f2b(fmaxf(b2f(v[5])*s1.y+h1v.y,0.f));
    o[6]=f2b(fmaxf(b2f(v[6])*s1.z+h1v.z,0.f)); o[7]=f2b(fmaxf(b2f(v[7])*s1.w+h1v.w,0.f));
    *reinterpret_cast<u16x8*>(h1 + i * 8) = o;
  }
}

__global__ void finalize_k(const float* __restrict__ st,
                           const float* __restrict__ gamma,
                           const float* __restrict__ beta,
                           float* __restrict__ out)   // scale[512], shift[512]
{
  int o = blockIdx.x*256 + threadIdx.x;
  const float inv = 1.f / 131072.f;                   // B*N*R
  float mean = st[o] * inv;
  float var  = st[512 + o] * inv - mean*mean;
  float sc   = gamma[o] * rsqrtf(var + 1e-5f);
  out[o]       = sc;
  out[512 + o] = beta[o] - mean * sc;
}

// ---------------------------------------------------------------------------
extern "C" void kernel_launch(void* const* d_in, const int* in_sizes, int n_in,
                              void* d_out, int out_size, void* d_ws, size_t ws_size,
                              hipStream_t stream)
{
  (void)in_sizes; (void)n_in; (void)out_size; (void)ws_size;
  const float* queries = (const float*)d_in[0];
  const float* feats   = (const float*)d_in[1];
  const float* Wq = (const float*)d_in[2];
  const float* bq = (const float*)d_in[3];
  const float* Wk = (const float*)d_in[4];
  const float* bk = (const float*)d_in[5];
  const float* Wv = (const float*)d_in[6];
  const float* bv = (const float*)d_in[7];
  const float* W1 = (const float*)d_in[8];
  const float* b1 = (const float*)d_in[9];
  const float* gamma = (const float*)d_in[10];
  const float* beta  = (const float*)d_in[11];
  const float* W2 = (const float*)d_in[12];
  const float* b2 = (const float*)d_in[13];

  // ws layout (bytes):
  //   [0, 268.4M)        : fT bf16 [B][NKF][256]; h1T (134.2M) aliases after
  //   [268.4M, 335.5M)   : qrT bf16 (live through kvattn: residual source)
  //   [335.5M, 402.7M)   : qT bf16 [B][NRQ][256]
  //   [402.7M, +8K)      : stats (sum512, sq512, scale512, shift512)
  //   [402.7M+8K, +920K) : wT bf16 weights + bKV fp32
  //   [416M, 483.1M)     : aggT bf16 [B][NRQ][256]
  char* ws = (char*)d_ws;
  u16*   fT    = (u16*)ws;
  u16*   h1T   = (u16*)ws;
  u16*   qrT   = (u16*)(ws + 268435456L);
  u16*   qT    = (u16*)(ws + 335544320L);
  float* stats = (float*)(ws + 402653184L);
  float* scale = stats + 1024;
  float* shift = stats + 1536;
  u16*   wT    = (u16*)(ws + 402661376L);
  u16*   wKV   = wT;                 // 512 x 256
  u16*   wQ    = wT + 131072;        // 256 x 256
  u16*   wW1   = wT + 196608;        // 512 x 256
  u16*   wW2   = wT + 327680;        // 256 x 512
  float* bKV   = (float*)(wT + 458752);
  u16*   aggT  = (u16*)(ws + 436207616L);

  cvtW_k<<<dim3(224), 256, 0, stream>>>(Wk, Wv, Wq, W1, W2, wT);
  prep_k<<<dim3(6), 256, 0, stream>>>(bk, bv, bKV, stats);

  // queries -> qrT bf16 [B][NRQ][256]
  transpose_k<<<dim3(NRQ/64, NB), 256, 0, stream>>>(queries, qrT, NRQ, (long)NRQ*256);

  // qT = qrT @ Wq^T + bq
  gemm_k<0, 256><<<dim3(512, 1, NB), 256, 0, stream>>>(
      qrT, (long)NRQ*256, 2, wQ, bq,
      qT, (long)NRQ*256, 256, nullptr, nullptr, nullptr, nullptr, 0);

  // feats -> fT bf16 [B][NKF][256]
  transpose_k<<<dim3(NKF/64, NB), 256, 0, stream>>>(feats, fT, NKF, (long)NKF*256);

  // fused kv-proj + attention -> aggT (+ qrT residual)
  kvattn_k<<<dim3(NKF/64, NB), 512, 0, stream>>>(fT, wKV, bKV, qT, qrT, aggT);

  // h1 = aggT @ W1^T + b1 -> bf16 + BN stats
  gemm_k<1, 256><<<dim3(1024, 1, NB), 256, 0, stream>>>(
      aggT, (long)NRQ*256, 4, wW1, b1,
      h1T, (long)NRQ*512, 512, stats, stats + 512, nullptr, nullptr, 0);

  finalize_k<<<dim3(2), 256, 0, stream>>>(stats, gamma, beta, scale);

  // h1 <- relu(bn(h1)) in place
  bnrelu_k<<<dim3(2048), 256, 0, stream>>>(h1T, scale, shift);

  // d_out = relu(h1' @ W2^T + b2 + aggT) -> fp32 [B][256][NRQ]
  gemm_k<2, 512><<<dim3(512, 1, NB), 256, 0, stream>>>(
      h1T, (long)NRQ*512, 2, wW2, b2,
      nullptr, 0, 256, nullptr, nullptr, aggT, (float*)d_out, (long)256*NRQ);
}

// Round 7
// 683.908 us; speedup vs baseline: 2.2624x; 1.2083x over previous
//
#include <hip/hip_runtime.h>
#include <hip/hip_bf16.h>

#define NB 4
#define NRQ 32768      // per-batch q-side rows  (n*4)
#define NKF 131072     // per-batch feats rows   (n*16)

using u16 = unsigned short;
typedef short bf16x8 __attribute__((ext_vector_type(8)));
typedef float f32x4  __attribute__((ext_vector_type(4)));
typedef u16   u16x8  __attribute__((ext_vector_type(8)));
typedef u16   u16x4  __attribute__((ext_vector_type(4)));
typedef u16   u16x2  __attribute__((ext_vector_type(2)));

#if defined(__has_builtin)
#  if __has_builtin(__builtin_amdgcn_fdot2_f32_bf16)
#    define HAVE_DOT2 1
#  endif
#endif
#ifndef HAVE_DOT2
#  define HAVE_DOT2 0
#endif

#if HAVE_DOT2
typedef __bf16 bfv2 __attribute__((ext_vector_type(2)));
union bpack { bf16x8 v; bfv2 p[4]; };
__device__ __forceinline__ float dot2(bfv2 a, bfv2 b, float c){
  return __builtin_amdgcn_fdot2_f32_bf16(a, b, c, false);
}
#endif
union vpack { bf16x8 v; u16 e[8]; };

__device__ __forceinline__ u16 f2b(float f){
  unsigned u = __float_as_uint(f);
  return (u16)((u + 0x7fffu + ((u >> 16) & 1u)) >> 16);  // RNE
}
__device__ __forceinline__ float b2f(u16 v){
  return __uint_as_float(((unsigned)v) << 16);
}

#define GLOAD16(g, l) __builtin_amdgcn_global_load_lds( \
    (const __attribute__((address_space(1))) unsigned int*)(g), \
    (__attribute__((address_space(3))) unsigned int*)(l), 16, 0, 0)

// ---------------------------------------------------------------------------
// Weight preconvert fp32 -> bf16 (k-contiguous rows, stacked)
// ---------------------------------------------------------------------------
__global__ __launch_bounds__(256) void cvtW_k(
    const float* __restrict__ Wk, const float* __restrict__ Wv,
    const float* __restrict__ Wq, const float* __restrict__ W1,
    const float* __restrict__ W2, u16* __restrict__ wT)
{
  long e = ((long)blockIdx.x * 256 + threadIdx.x) * 8;
  const float* src; long off;
  if      (e < 65536)  { src = Wk; off = e; }
  else if (e < 131072) { src = Wv; off = e - 65536; }
  else if (e < 196608) { src = Wq; off = e - 131072; }
  else if (e < 327680) { src = W1; off = e - 196608; }
  else                 { src = W2; off = e - 327680; }
  float4 f0 = *reinterpret_cast<const float4*>(src + off);
  float4 f1 = *reinterpret_cast<const float4*>(src + off + 4);
  u16x8 p;
  p[0]=f2b(f0.x); p[1]=f2b(f0.y); p[2]=f2b(f0.z); p[3]=f2b(f0.w);
  p[4]=f2b(f1.x); p[5]=f2b(f1.y); p[6]=f2b(f1.z); p[7]=f2b(f1.w);
  *reinterpret_cast<u16x8*>(wT + e) = p;
}

// bias stack [bk;bv] + zero BN stat accumulators
__global__ void prep_k(const float* __restrict__ bk, const float* __restrict__ bv,
                       float* __restrict__ bKV, float* __restrict__ stats)
{
  int i = blockIdx.x * 256 + threadIdx.x;       // grid 6*256 = 1536
  if (i < 512)       bKV[i] = (i < 256) ? bk[i] : bv[i - 256];
  else               stats[i - 512] = 0.f;      // 1024 floats: sum, sumsq
}

// ---------------------------------------------------------------------------
// Transpose+convert: in fp32 [B][256][NCtot] -> out bf16 [B][NCtot][256].
// ---------------------------------------------------------------------------
__global__ __launch_bounds__(256) void transpose_k(
    const float* __restrict__ in, u16* __restrict__ out,
    int NCtot, long outBatch)
{
  __shared__ u16 sT[64][264];
  const int t = threadIdx.x, b = blockIdx.y;
  const int nr0 = blockIdx.x * 64;
  const int cb = t >> 2, nrq = t & 3;
  const long ib = (long)b * 256 * NCtot + nr0;

  #pragma unroll
  for (int ci = 0; ci < 4; ++ci){
    const int c = cb + ci * 64;
    const float* src = in + ib + (long)c * NCtot + nrq * 16;
    #pragma unroll
    for (int j = 0; j < 4; ++j){
      float4 f = *reinterpret_cast<const float4*>(src + j * 4);
      int nr = nrq * 16 + j * 4;
      sT[nr+0][c] = f2b(f.x); sT[nr+1][c] = f2b(f.y);
      sT[nr+2][c] = f2b(f.z); sT[nr+3][c] = f2b(f.w);
    }
  }
  __syncthreads();
  const int row = t >> 2, qtr = t & 3;
  u16* orow = out + (long)b * outBatch + (long)(nr0 + row) * 256 + qtr * 64;
  #pragma unroll
  for (int i = 0; i < 8; ++i)
    *reinterpret_cast<u16x8*>(orow + i * 8) =
        *reinterpret_cast<const u16x8*>(&sT[row][qtr * 64 + i * 8]);
}

// ---------------------------------------------------------------------------
// GEMM: C[rows x NCH] = A[rows x KD] (bf16 k-contig) * Wb[NCH x KD]^T + bias.
// Both operands via global_load_lds, 2-phase double-buffered, 128x128 tile.
// MODE 0: bf16 C. MODE 1: + per-ch sum/sumsq atomics.
// MODE 2: out = relu(acc + bias + residT[row][ch]) -> fp32 outF [ch][row].
// ---------------------------------------------------------------------------
template<int MODE, int KD>
__global__ __launch_bounds__(256) void gemm_k(
    const u16* __restrict__ A, long aBatch, int chTiles,
    const u16* __restrict__ Wb, const float* __restrict__ bias,
    u16* __restrict__ outH, long oBatch, int NCH,
    float* __restrict__ statSum, float* __restrict__ statSq,
    const u16* __restrict__ residT,
    float* __restrict__ outF, long fBatch)
{
  __shared__ __align__(16) char sA[2][16384];
  __shared__ __align__(16) char sB[2][16384];

  const int t = threadIdx.x, lane = t & 63, wid = t >> 6;
  const int wm = wid >> 1, wn = wid & 1;
  const int b = blockIdx.z;

  const int nwg = gridDim.x, orig = blockIdx.x;
  const int qq = nwg >> 3, rr = nwg & 7, xcd = orig & 7, pos = orig >> 3;
  const int wg = (xcd < rr ? xcd * (qq + 1) : rr * (qq + 1) + (xcd - rr) * qq) + pos;
  const int rowT = wg / chTiles, chT = wg % chTiles;

  const u16* Ab = A + (long)b * aBatch + (long)rowT * 128 * KD;
  const u16* Wt = Wb + (long)chT * 128 * KD;
  const int sub = lane >> 3, kc8 = ((lane & 7) ^ sub) * 8;

  f32x4 acc[4][4];
  #pragma unroll
  for (int i = 0; i < 4; ++i)
    #pragma unroll
    for (int j = 0; j < 4; ++j) acc[i][j] = (f32x4){0.f,0.f,0.f,0.f};

  auto STAGE = [&](int buf, int ks){
    const int k0 = ks * 64;
    #pragma unroll
    for (int i = 0; i < 4; ++i){
      const int chunk = wid * 4 + i;
      GLOAD16(Ab + (long)(chunk*8 + sub)*KD + k0 + kc8, sA[buf] + chunk*1024);
      GLOAD16(Wt + (long)(chunk*8 + sub)*KD + k0 + kc8, sB[buf] + chunk*1024);
    }
  };

  constexpr int NT = KD / 64;
  STAGE(0, 0);
  __syncthreads();
  int cur = 0;
  for (int ks = 0; ks < NT; ++ks){
    if (ks + 1 < NT) STAGE(cur ^ 1, ks + 1);
    const char* pA = sA[cur]; const char* pB = sB[cur];
    #pragma unroll
    for (int kk = 0; kk < 2; ++kk){
      bf16x8 af[4], bf[4];
      #pragma unroll
      for (int mi = 0; mi < 4; ++mi){
        int m = wm*64 + mi*16 + (lane & 15);
        af[mi] = *reinterpret_cast<const bf16x8*>(
            pA + ((m*128 + kk*64 + (lane>>4)*16) ^ ((m & 7) << 4)));
      }
      #pragma unroll
      for (int ni = 0; ni < 4; ++ni){
        int c = wn*64 + ni*16 + (lane & 15);
        bf[ni] = *reinterpret_cast<const bf16x8*>(
            pB + ((c*128 + kk*64 + (lane>>4)*16) ^ ((c & 7) << 4)));
      }
      #pragma unroll
      for (int mi = 0; mi < 4; ++mi)
        #pragma unroll
        for (int ni = 0; ni < 4; ++ni)
          acc[mi][ni] = __builtin_amdgcn_mfma_f32_16x16x32_bf16(
              af[mi], bf[ni], acc[mi][ni], 0, 0, 0);
    }
    __syncthreads();
    cur ^= 1;
  }

  int chI[4]; float bv[4];
  #pragma unroll
  for (int ni = 0; ni < 4; ++ni){
    int ch = chT*128 + wn*64 + ni*16 + (lane & 15);
    chI[ni] = ch;
    bv[ni] = bias[ch];
  }
  if (MODE <= 1){
    float s[4] = {0,0,0,0}, sq[4] = {0,0,0,0};
    u16* outb = outH + (long)b * oBatch;
    #pragma unroll
    for (int mi = 0; mi < 4; ++mi){
      #pragma unroll
      for (int j = 0; j < 4; ++j){
        const long row = rowT*128 + wm*64 + mi*16 + (lane>>4)*4 + j;
        #pragma unroll
        for (int ni = 0; ni < 4; ++ni){
          float v = acc[mi][ni][j] + bv[ni];
          outb[row * NCH + chI[ni]] = f2b(v);
          if (MODE == 1){ s[ni] += v; sq[ni] += v * v; }
        }
      }
    }
    if (MODE == 1){
      #pragma unroll
      for (int ni = 0; ni < 4; ++ni){
        s[ni]  += __shfl_xor(s[ni], 16);  s[ni]  += __shfl_xor(s[ni], 32);
        sq[ni] += __shfl_xor(sq[ni], 16); sq[ni] += __shfl_xor(sq[ni], 32);
      }
      if (lane < 16){
        #pragma unroll
        for (int ni = 0; ni < 4; ++ni){
          atomicAdd(&statSum[chI[ni]], s[ni]);
          atomicAdd(&statSq[chI[ni]],  sq[ni]);
        }
      }
    }
  } else {
    const u16* rb = residT + (long)b * ((long)NRQ * 256);
    #pragma unroll
    for (int mi = 0; mi < 4; ++mi){
      const int nr0 = rowT*128 + wm*64 + mi*16 + (lane>>4)*4;
      #pragma unroll
      for (int ni = 0; ni < 4; ++ni){
        float4 o;
        o.x = fmaxf(acc[mi][ni][0] + bv[ni] + b2f(rb[(long)(nr0+0)*256 + chI[ni]]), 0.f);
        o.y = fmaxf(acc[mi][ni][1] + bv[ni] + b2f(rb[(long)(nr0+1)*256 + chI[ni]]), 0.f);
        o.z = fmaxf(acc[mi][ni][2] + bv[ni] + b2f(rb[(long)(nr0+2)*256 + chI[ni]]), 0.f);
        o.w = fmaxf(acc[mi][ni][3] + bv[ni] + b2f(rb[(long)(nr0+3)*256 + chI[ni]]), 0.f);
        *reinterpret_cast<float4*>(outF + (long)b*fBatch + (long)chI[ni]*NRQ + nr0) = o;
      }
    }
  }
}

// ---------------------------------------------------------------------------
// Fused kv-projection + attention, v3.
// Block = 512 thr (8 waves), 64 feat rows (4 points) x 512 kv-channels.
// A staged IN-KERNEL from fp32 feats (convert+transpose, kills the feats
// transpose kernel); W double-buffered via global_load_lds, BK=32.
// k -> sK [64 rows][256 ch] (pitch 528B); v -> sVT TRANSPOSED [cv][kk]
// (u16x4 writes). Attention: 2 waves/point; QK^T and PV via v_dot2_f32_bf16
// when available. LDS 72KB -> 2 blocks/CU.
// ---------------------------------------------------------------------------
__global__ __launch_bounds__(512, 4) void kvattn_k(
    const float* __restrict__ feats, const u16* __restrict__ wKV,
    const float* __restrict__ bKV, const u16* __restrict__ qT,
    const u16* __restrict__ qrT, u16* __restrict__ aggT)
{
  __shared__ __align__(16) char LDS[73728];
  char* sAg = LDS;                      // GEMM A: 2 x 4KB [64 r][4 slot swz]
  char* sW  = LDS + 8192;               // GEMM W: 2 x 32KB [512 ch][4 slot swz]
  char* sK  = LDS;                      // attn K: [64 rows][528B]
  char* sVT = LDS + 33792;              // attn V^T: [4 p][256 cv][16 kk]
#if HAVE_DOT2
  char* sSb = LDS + 66560;              // P bf16 pairs: [16 ph][4 r][8 kp x4B]
#else
  float* sS = (float*)(LDS + 66560);    // P fp32: [16 ph][16 kk][4 r]
#endif

  const int t = threadIdx.x, lane = t & 63, wid = t >> 6;
  const int wr = wid >> 2, wc = wid & 3;       // 2 x 4 waves for GEMM
  const int b = blockIdx.y;
  const long row0 = (long)blockIdx.x * 64;

  // A staging map: thread -> (k-elem chL, row quad nq)
  const int chL = t >> 4, nq = t & 15;
  const float* fbase = feats + (long)b * 256 * NKF + row0 + nq * 4;

  auto STAGEW = [&](int buf, int ks){
    const int k0 = ks * 32;
    #pragma unroll
    for (int i = 0; i < 4; ++i){
      const int cw = wid * 4 + i;
      const int ch = cw * 16 + (lane >> 2), jd = lane & 3;
      GLOAD16(wKV + (long)ch * 256 + k0 + ((jd ^ ((ch >> 1) & 3)) * 8),
              sW + buf * 32768 + cw * 1024);
    }
  };
  auto WRITEA = [&](int buf, float4 f){
    #pragma unroll
    for (int i = 0; i < 4; ++i){
      const int r = nq * 4 + i;
      const int byte = buf*4096 + r*64 + ((((chL>>3) ^ ((r>>1)&3))) << 4) + (chL & 7)*2;
      float e = (i == 0) ? f.x : (i == 1) ? f.y : (i == 2) ? f.z : f.w;
      *reinterpret_cast<u16*>(sAg + byte) = f2b(e);
    }
  };

  f32x4 acc[2][8];
  #pragma unroll
  for (int i = 0; i < 2; ++i)
    #pragma unroll
    for (int j = 0; j < 8; ++j) acc[i][j] = (f32x4){0.f,0.f,0.f,0.f};

  {
    float4 a0 = *reinterpret_cast<const float4*>(fbase + (long)chL * NKF);
    STAGEW(0, 0);
    WRITEA(0, a0);
  }
  __syncthreads();
  int cur = 0;
  for (int ks = 0; ks < 8; ++ks){
    float4 an;
    if (ks < 7){
      an = *reinterpret_cast<const float4*>(fbase + (long)((ks+1)*32 + chL) * NKF);
      STAGEW(cur ^ 1, ks + 1);
    }
    const char* pA = sAg + cur * 4096;
    const char* pW = sW  + cur * 32768;
    bf16x8 af[2];
    #pragma unroll
    for (int mi = 0; mi < 2; ++mi){
      const int m = wr*32 + mi*16 + (lane & 15);
      af[mi] = *reinterpret_cast<const bf16x8*>(
          pA + m*64 + (((lane>>4) ^ ((m>>1)&3)) * 16));
    }
    #pragma unroll
    for (int ni = 0; ni < 8; ++ni){
      const int ch = wc*128 + ni*16 + (lane & 15);
      bf16x8 bf = *reinterpret_cast<const bf16x8*>(
          pW + ch*64 + (((lane>>4) ^ ((ch>>1)&3)) * 16));
      acc[0][ni] = __builtin_amdgcn_mfma_f32_16x16x32_bf16(af[0], bf, acc[0][ni], 0,0,0);
      acc[1][ni] = __builtin_amdgcn_mfma_f32_16x16x32_bf16(af[1], bf, acc[1][ni], 0,0,0);
    }
    if (ks < 7) WRITEA(cur ^ 1, an);
    __syncthreads();
    cur ^= 1;
  }

  // ---- C (+bias) -> sK (ch 0-255) / sVT transposed (ch 256-511)
  {
    float bv[8];
    #pragma unroll
    for (int ni = 0; ni < 8; ++ni) bv[ni] = bKV[wc*128 + ni*16 + (lane & 15)];
    if (wc < 2){
      #pragma unroll
      for (int mi = 0; mi < 2; ++mi){
        const int p2 = wr*2 + mi;
        #pragma unroll
        for (int ni = 0; ni < 8; ++ni){
          const int ch = wc*128 + ni*16 + (lane & 15);
          #pragma unroll
          for (int j = 0; j < 4; ++j){
            const int kk2 = (lane>>4)*4 + j;
            *reinterpret_cast<u16*>(sK + (p2*16 + kk2)*528 + ch*2) =
                f2b(acc[mi][ni][j] + bv[ni]);
          }
        }
      }
    } else {
      #pragma unroll
      for (int mi = 0; mi < 2; ++mi){
        const int p2 = wr*2 + mi;
        #pragma unroll
        for (int ni = 0; ni < 8; ++ni){
          const int cv = (wc-2)*128 + ni*16 + (lane & 15);
          u16x4 w;
          #pragma unroll
          for (int j = 0; j < 4; ++j) w[j] = f2b(acc[mi][ni][j] + bv[ni]);
          *reinterpret_cast<u16x4*>(sVT + p2*8192 + cv*32 + (lane>>4)*8) = w;
        }
      }
    }
  }
  __syncthreads();

  // ---- attention: wave = (rh, p); phase A lane = (h, kk)
  const int p = wid & 3, rh = wid >> 2;
  const int nqg = blockIdx.x * 4 + p;
  {
    const int h = lane >> 4, kk = lane & 15;
    const u16* qb = qT + ((long)b*NRQ + (long)nqg*4 + rh*2)*256 + h*64;
    const char* kr = sK + (p*16 + kk)*528 + h*128;
    float l0 = 0.f, l1 = 0.f;
#if HAVE_DOT2
    #pragma unroll
    for (int d8 = 0; d8 < 8; ++d8){
      bpack K8, Q0, Q1;
      K8.v = *reinterpret_cast<const bf16x8*>(kr + d8*16);
      Q0.v = *reinterpret_cast<const bf16x8*>(qb + d8*8);
      Q1.v = *reinterpret_cast<const bf16x8*>(qb + 256 + d8*8);
      #pragma unroll
      for (int pi = 0; pi < 4; ++pi){
        l0 = dot2(K8.p[pi], Q0.p[pi], l0);
        l1 = dot2(K8.p[pi], Q1.p[pi], l1);
      }
    }
#else
    #pragma unroll
    for (int d8 = 0; d8 < 8; ++d8){
      vpack K8, Q0, Q1;
      K8.v = *reinterpret_cast<const bf16x8*>(kr + d8*16);
      Q0.v = *reinterpret_cast<const bf16x8*>(qb + d8*8);
      Q1.v = *reinterpret_cast<const bf16x8*>(qb + 256 + d8*8);
      #pragma unroll
      for (int e = 0; e < 8; ++e){
        float kf = b2f(K8.e[e]);
        l0 = fmaf(kf, b2f(Q0.e[e]), l0);
        l1 = fmaf(kf, b2f(Q1.e[e]), l1);
      }
    }
#endif
    float pr[2]; float lv[2] = {l0, l1};
    #pragma unroll
    for (int r = 0; r < 2; ++r){
      float x = lv[r] * 0.125f;
      float m = x;
      #pragma unroll
      for (int off = 1; off < 16; off <<= 1) m = fmaxf(m, __shfl_xor(m, off));
      float e = __expf(x - m);
      float ssum = e;
      #pragma unroll
      for (int off = 1; off < 16; off <<= 1) ssum += __shfl_xor(ssum, off);
      pr[r] = e / ssum;
    }
#if HAVE_DOT2
    float o0 = __shfl_xor(pr[0], 1), o1 = __shfl_xor(pr[1], 1);
    if (!(kk & 1)){
      char* sb = sSb + (p*4 + h)*128 + (kk>>1)*4;
      u16x2 w0; w0[0] = f2b(pr[0]); w0[1] = f2b(o0);
      u16x2 w1; w1[0] = f2b(pr[1]); w1[1] = f2b(o1);
      *reinterpret_cast<u16x2*>(sb + (rh*2)*32)     = w0;
      *reinterpret_cast<u16x2*>(sb + (rh*2 + 1)*32) = w1;
    }
#else
    *reinterpret_cast<float2*>(sS + ((p*4 + h)*16 + kk)*4 + rh*2) =
        make_float2(pr[0], pr[1]);
#endif
  }
  __syncthreads();

  // ---- phase B: agg = v @ soft^T + qrT residual. lane -> 2 channels
  {
    const int cv0 = rh*128 + lane*2;
    const int h = cv0 >> 6;
    const char* vb = sVT + p*8192 + cv0*32;
    float ar[4][2];
#if HAVE_DOT2
    bpack va0, va1, vc0, vc1;
    va0.v = *reinterpret_cast<const bf16x8*>(vb);
    va1.v = *reinterpret_cast<const bf16x8*>(vb + 16);
    vc0.v = *reinterpret_cast<const bf16x8*>(vb + 32);
    vc1.v = *reinterpret_cast<const bf16x8*>(vb + 48);
    #pragma unroll
    for (int r = 0; r < 4; ++r){
      bpack s0, s1;
      const char* sb = sSb + (p*4 + h)*128 + r*32;
      s0.v = *reinterpret_cast<const bf16x8*>(sb);
      s1.v = *reinterpret_cast<const bf16x8*>(sb + 16);
      float a0 = 0.f, a1 = 0.f;
      #pragma unroll
      for (int pi = 0; pi < 4; ++pi){
        a0 = dot2(va0.p[pi], s0.p[pi], a0);
        a1 = dot2(vc0.p[pi], s0.p[pi], a1);
      }
      #pragma unroll
      for (int pi = 0; pi < 4; ++pi){
        a0 = dot2(va1.p[pi], s1.p[pi], a0);
        a1 = dot2(vc1.p[pi], s1.p[pi], a1);
      }
      ar[r][0] = a0; ar[r][1] = a1;
    }
#else
    vpack va0, va1, vc0, vc1;
    va0.v = *reinterpret_cast<const bf16x8*>(vb);
    va1.v = *reinterpret_cast<const bf16x8*>(vb + 16);
    vc0.v = *reinterpret_cast<const bf16x8*>(vb + 32);
    vc1.v = *reinterpret_cast<const bf16x8*>(vb + 48);
    #pragma unroll
    for (int r = 0; r < 4; ++r){ ar[r][0] = 0.f; ar[r][1] = 0.f; }
    #pragma unroll
    for (int kk = 0; kk < 16; ++kk){
      float v0 = b2f(kk < 8 ? va0.e[kk & 7] : va1.e[kk & 7]);
      float v1 = b2f(kk < 8 ? vc0.e[kk & 7] : vc1.e[kk & 7]);
      float4 sv = *reinterpret_cast<const float4*>(sS + ((p*4 + h)*16 + kk)*4);
      ar[0][0] += sv.x*v0; ar[0][1] += sv.x*v1;
      ar[1][0] += sv.y*v0; ar[1][1] += sv.y*v1;
      ar[2][0] += sv.z*v0; ar[2][1] += sv.z*v1;
      ar[3][0] += sv.w*v0; ar[3][1] += sv.w*v1;
    }
#endif
    const u16* rq = qrT + ((long)b*NRQ + (long)nqg*4)*256 + cv0;
    u16* ob = aggT + ((long)b*NRQ + (long)nqg*4)*256 + cv0;
    #pragma unroll
    for (int r = 0; r < 4; ++r){
      u16x2 q2 = *reinterpret_cast<const u16x2*>(rq + r*256);
      u16x2 pk;
      pk[0] = f2b(ar[r][0] + b2f(q2[0]));
      pk[1] = f2b(ar[r][1] + b2f(q2[1]));
      *reinterpret_cast<u16x2*>(ob + r*256) = pk;
    }
  }
}

// ---------------------------------------------------------------------------
__global__ void bnrelu_k(u16* __restrict__ h1, const float* __restrict__ sc,
                         const float* __restrict__ sh)
{
  const long total = (long)NB * NRQ * 512 / 8;
  for (long i = (long)blockIdx.x * blockDim.x + threadIdx.x; i < total;
       i += (long)gridDim.x * blockDim.x){
    u16x8 v = *reinterpret_cast<const u16x8*>(h1 + i * 8);
    int chb = (int)((i * 8) & 511);
    float4 s0 = *reinterpret_cast<const float4*>(sc + chb);
    float4 s1 = *reinterpret_cast<const float4*>(sc + chb + 4);
    float4 h0 = *reinterpret_cast<const float4*>(sh + chb);
    float4 h1v= *reinterpret_cast<const float4*>(sh + chb + 4);
    u16x8 o;
    o[0]=f2b(fmaxf(b2f(v[0])*s0.x+h0.x ,0.f)); o[1]=f2b(fmaxf(b2f(v[1])*s0.y+h0.y ,0.f));
    o[2]=f2b(fmaxf(b2f(v[2])*s0.z+h0.z ,0.f)); o[3]=f2b(fmaxf(b2f(v[3])*s0.w+h0.w ,0.f));
    o[4]=f2b(fmaxf(b2f(v[4])*s1.x+h1v.x,0.f)); o[5]=f2b(fmaxf(b2f(v[5])*s1.y+h1v.y,0.f));
    o[6]=f2b(fmaxf(b2f(v[6])*s1.z+h1v.z,0.f)); o[7]=f2b(fmaxf(b2f(v[7])*s1.w+h1v.w,0.f));
    *reinterpret_cast<u16x8*>(h1 + i * 8) = o;
  }
}

__global__ void finalize_k(const float* __restrict__ st,
                           const float* __restrict__ gamma,
                           const float* __restrict__ beta,
                           float* __restrict__ out)   // scale[512], shift[512]
{
  int o = blockIdx.x*256 + threadIdx.x;
  const float inv = 1.f / 131072.f;                   // B*N*R
  float mean = st[o] * inv;
  float var  = st[512 + o] * inv - mean*mean;
  float sc   = gamma[o] * rsqrtf(var + 1e-5f);
  out[o]       = sc;
  out[512 + o] = beta[o] - mean * sc;
}

// ---------------------------------------------------------------------------
extern "C" void kernel_launch(void* const* d_in, const int* in_sizes, int n_in,
                              void* d_out, int out_size, void* d_ws, size_t ws_size,
                              hipStream_t stream)
{
  (void)in_sizes; (void)n_in; (void)out_size; (void)ws_size;
  const float* queries = (const float*)d_in[0];
  const float* feats   = (const float*)d_in[1];
  const float* Wq = (const float*)d_in[2];
  const float* bq = (const float*)d_in[3];
  const float* Wk = (const float*)d_in[4];
  const float* bk = (const float*)d_in[5];
  const float* Wv = (const float*)d_in[6];
  const float* bv = (const float*)d_in[7];
  const float* W1 = (const float*)d_in[8];
  const float* b1 = (const float*)d_in[9];
  const float* gamma = (const float*)d_in[10];
  const float* beta  = (const float*)d_in[11];
  const float* W2 = (const float*)d_in[12];
  const float* b2 = (const float*)d_in[13];

  // ws layout (bytes):
  //   [0, 134.2M)        : h1T bf16 [B][NRQ][512]
  //   [134.2M, 201.3M)   : qrT bf16 [B][NRQ][256]
  //   [201.3M, 268.4M)   : qT bf16
  //   [268.4M, 335.5M)   : aggT bf16
  //   [335.5M, +8K)      : stats; then wT weights + bKV
  char* ws = (char*)d_ws;
  u16*   h1T   = (u16*)ws;
  u16*   qrT   = (u16*)(ws + 134217728L);
  u16*   qT    = (u16*)(ws + 201326592L);
  u16*   aggT  = (u16*)(ws + 268435456L);
  float* stats = (float*)(ws + 335544320L);
  float* scale = stats + 1024;
  float* shift = stats + 1536;
  u16*   wT    = (u16*)(ws + 335552512L);
  u16*   wKV   = wT;                 // 512 x 256
  u16*   wQ    = wT + 131072;        // 256 x 256
  u16*   wW1   = wT + 196608;        // 512 x 256
  u16*   wW2   = wT + 327680;        // 256 x 512
  float* bKV   = (float*)(wT + 458752);

  cvtW_k<<<dim3(224), 256, 0, stream>>>(Wk, Wv, Wq, W1, W2, wT);
  prep_k<<<dim3(6), 256, 0, stream>>>(bk, bv, bKV, stats);

  // queries -> qrT bf16 [B][NRQ][256]
  transpose_k<<<dim3(NRQ/64, NB), 256, 0, stream>>>(queries, qrT, NRQ, (long)NRQ*256);

  // qT = qrT @ Wq^T + bq
  gemm_k<0, 256><<<dim3(512, 1, NB), 256, 0, stream>>>(
      qrT, (long)NRQ*256, 2, wQ, bq,
      qT, (long)NRQ*256, 256, nullptr, nullptr, nullptr, nullptr, 0);

  // fused kv-proj + attention (reads fp32 feats directly) -> aggT
  kvattn_k<<<dim3(NKF/64, NB), 512, 0, stream>>>(feats, wKV, bKV, qT, qrT, aggT);

  // h1 = aggT @ W1^T + b1 -> bf16 + BN stats
  gemm_k<1, 256><<<dim3(1024, 1, NB), 256, 0, stream>>>(
      aggT, (long)NRQ*256, 4, wW1, b1,
      h1T, (long)NRQ*512, 512, stats, stats + 512, nullptr, nullptr, 0);

  finalize_k<<<dim3(2), 256, 0, stream>>>(stats, gamma, beta, scale);

  // h1 <- relu(bn(h1)) in place
  bnrelu_k<<<dim3(2048), 256, 0, stream>>>(h1T, scale, shift);

  // d_out = relu(h1' @ W2^T + b2 + aggT) -> fp32 [B][256][NRQ]
  gemm_k<2, 512><<<dim3(512, 1, NB), 256, 0, stream>>>(
      h1T, (long)NRQ*512, 2, wW2, b2,
      nullptr, 0, 256, nullptr, nullptr, aggT, (float*)d_out, (long)256*NRQ);
}

// Round 8
// 649.347 us; speedup vs baseline: 2.3828x; 1.0532x over previous
//
#include <hip/hip_runtime.h>
#include <hip/hip_bf16.h>

#define NB 4
#define NRQ 32768      // per-batch q-side rows  (n*4)
#define NKF 131072     // per-batch feats rows   (n*16)

using u16 = unsigned short;
typedef short bf16x8 __attribute__((ext_vector_type(8)));
typedef float f32x4  __attribute__((ext_vector_type(4)));
typedef u16   u16x8  __attribute__((ext_vector_type(8)));
typedef u16   u16x4  __attribute__((ext_vector_type(4)));
typedef u16   u16x2  __attribute__((ext_vector_type(2)));

#if defined(__has_builtin)
#  if __has_builtin(__builtin_amdgcn_fdot2_f32_bf16)
#    define HAVE_DOT2 1
#  endif
#endif
#ifndef HAVE_DOT2
#  define HAVE_DOT2 0
#endif

#if HAVE_DOT2
typedef __bf16 bfv2 __attribute__((ext_vector_type(2)));
union bpack { bf16x8 v; bfv2 p[4]; };
__device__ __forceinline__ float dot2(bfv2 a, bfv2 b, float c){
  return __builtin_amdgcn_fdot2_f32_bf16(a, b, c, false);
}
#endif
union vpack { bf16x8 v; u16 e[8]; };

__device__ __forceinline__ u16 f2b(float f){
  unsigned u = __float_as_uint(f);
  return (u16)((u + 0x7fffu + ((u >> 16) & 1u)) >> 16);  // RNE
}
__device__ __forceinline__ float b2f(u16 v){
  return __uint_as_float(((unsigned)v) << 16);
}

#define GLOAD16(g, l) __builtin_amdgcn_global_load_lds( \
    (const __attribute__((address_space(1))) unsigned int*)(g), \
    (__attribute__((address_space(3))) unsigned int*)(l), 16, 0, 0)

// ---------------------------------------------------------------------------
// Weight preconvert fp32 -> bf16 (k-contiguous rows, stacked)
// ---------------------------------------------------------------------------
__global__ __launch_bounds__(256) void cvtW_k(
    const float* __restrict__ Wk, const float* __restrict__ Wv,
    const float* __restrict__ Wq, const float* __restrict__ W1,
    const float* __restrict__ W2, u16* __restrict__ wT)
{
  long e = ((long)blockIdx.x * 256 + threadIdx.x) * 8;
  const float* src; long off;
  if      (e < 65536)  { src = Wk; off = e; }
  else if (e < 131072) { src = Wv; off = e - 65536; }
  else if (e < 196608) { src = Wq; off = e - 131072; }
  else if (e < 327680) { src = W1; off = e - 196608; }
  else                 { src = W2; off = e - 327680; }
  float4 f0 = *reinterpret_cast<const float4*>(src + off);
  float4 f1 = *reinterpret_cast<const float4*>(src + off + 4);
  u16x8 p;
  p[0]=f2b(f0.x); p[1]=f2b(f0.y); p[2]=f2b(f0.z); p[3]=f2b(f0.w);
  p[4]=f2b(f1.x); p[5]=f2b(f1.y); p[6]=f2b(f1.z); p[7]=f2b(f1.w);
  *reinterpret_cast<u16x8*>(wT + e) = p;
}

// bias stack [bk;bv] + zero BN stat accumulators
__global__ void prep_k(const float* __restrict__ bk, const float* __restrict__ bv,
                       float* __restrict__ bKV, float* __restrict__ stats)
{
  int i = blockIdx.x * 256 + threadIdx.x;       // grid 6*256 = 1536
  if (i < 512)       bKV[i] = (i < 256) ? bk[i] : bv[i - 256];
  else               stats[i - 512] = 0.f;      // 1024 floats: sum, sumsq
}

// ---------------------------------------------------------------------------
// Transpose+convert: in fp32 [B][256][NCtot] -> out bf16 [B][NCtot][256].
// ---------------------------------------------------------------------------
__global__ __launch_bounds__(256) void transpose_k(
    const float* __restrict__ in, u16* __restrict__ out,
    int NCtot, long outBatch)
{
  __shared__ u16 sT[64][264];
  const int t = threadIdx.x, b = blockIdx.y;
  const int nr0 = blockIdx.x * 64;
  const int cb = t >> 2, nrq = t & 3;
  const long ib = (long)b * 256 * NCtot + nr0;

  #pragma unroll
  for (int ci = 0; ci < 4; ++ci){
    const int c = cb + ci * 64;
    const float* src = in + ib + (long)c * NCtot + nrq * 16;
    #pragma unroll
    for (int j = 0; j < 4; ++j){
      float4 f = *reinterpret_cast<const float4*>(src + j * 4);
      int nr = nrq * 16 + j * 4;
      sT[nr+0][c] = f2b(f.x); sT[nr+1][c] = f2b(f.y);
      sT[nr+2][c] = f2b(f.z); sT[nr+3][c] = f2b(f.w);
    }
  }
  __syncthreads();
  const int row = t >> 2, qtr = t & 3;
  u16* orow = out + (long)b * outBatch + (long)(nr0 + row) * 256 + qtr * 64;
  #pragma unroll
  for (int i = 0; i < 8; ++i)
    *reinterpret_cast<u16x8*>(orow + i * 8) =
        *reinterpret_cast<const u16x8*>(&sT[row][qtr * 64 + i * 8]);
}

// ---------------------------------------------------------------------------
// GEMM: C[rows x NCH] = A[rows x KD] (bf16 k-contig) * Wb[NCH x KD]^T + bias.
// MODE 0: bf16 C. MODE 1: + per-ch sum/sumsq atomics.
// MODE 2: out = relu(acc + bias + residT[row][ch]) -> fp32 outF [ch][row].
// MODE 3: MODE 2 + A staged through registers with per-k BN scale/shift+relu.
// ---------------------------------------------------------------------------
template<int MODE, int KD>
__global__ __launch_bounds__(256) void gemm_k(
    const u16* __restrict__ A, long aBatch, int chTiles,
    const u16* __restrict__ Wb, const float* __restrict__ bias,
    u16* __restrict__ outH, long oBatch, int NCH,
    float* __restrict__ statSum, float* __restrict__ statSq,
    const float* __restrict__ xsc, const float* __restrict__ xsh,
    const u16* __restrict__ residT,
    float* __restrict__ outF, long fBatch)
{
  __shared__ __align__(16) char sA[2][16384];
  __shared__ __align__(16) char sB[2][16384];

  const int t = threadIdx.x, lane = t & 63, wid = t >> 6;
  const int wm = wid >> 1, wn = wid & 1;
  const int b = blockIdx.z;

  const int nwg = gridDim.x, orig = blockIdx.x;
  const int qq = nwg >> 3, rr = nwg & 7, xcd = orig & 7, pos = orig >> 3;
  const int wg = (xcd < rr ? xcd * (qq + 1) : rr * (qq + 1) + (xcd - rr) * qq) + pos;
  const int rowT = wg / chTiles, chT = wg % chTiles;

  const u16* Ab = A + (long)b * aBatch + (long)rowT * 128 * KD;
  const u16* Wt = Wb + (long)chT * 128 * KD;
  const int sub = lane >> 3, kc8 = ((lane & 7) ^ sub) * 8;

  f32x4 acc[4][4];
  #pragma unroll
  for (int i = 0; i < 4; ++i)
    #pragma unroll
    for (int j = 0; j < 4; ++j) acc[i][j] = (f32x4){0.f,0.f,0.f,0.f};

  auto STAGE = [&](int buf, int ks){
    const int k0 = ks * 64;
    if constexpr (MODE == 3){
      // A: reg-staged + BN(scale,shift)+ReLU, swizzled u16x8 stores
      const int wrow = t >> 1, whalf = t & 1;
      const u16* arow = Ab + (long)wrow * KD + k0 + whalf * 32;
      #pragma unroll
      for (int i = 0; i < 4; ++i){
        u16x8 v = *reinterpret_cast<const u16x8*>(arow + i * 8);
        const int kb = k0 + whalf*32 + i*8;
        float4 s0 = *reinterpret_cast<const float4*>(xsc + kb);
        float4 s1 = *reinterpret_cast<const float4*>(xsc + kb + 4);
        float4 h0 = *reinterpret_cast<const float4*>(xsh + kb);
        float4 h1 = *reinterpret_cast<const float4*>(xsh + kb + 4);
        u16x8 o;
        o[0]=f2b(fmaxf(b2f(v[0])*s0.x+h0.x,0.f));
        o[1]=f2b(fmaxf(b2f(v[1])*s0.y+h0.y,0.f));
        o[2]=f2b(fmaxf(b2f(v[2])*s0.z+h0.z,0.f));
        o[3]=f2b(fmaxf(b2f(v[3])*s0.w+h0.w,0.f));
        o[4]=f2b(fmaxf(b2f(v[4])*s1.x+h1.x,0.f));
        o[5]=f2b(fmaxf(b2f(v[5])*s1.y+h1.y,0.f));
        o[6]=f2b(fmaxf(b2f(v[6])*s1.z+h1.z,0.f));
        o[7]=f2b(fmaxf(b2f(v[7])*s1.w+h1.w,0.f));
        *reinterpret_cast<u16x8*>(
            sA[buf] + ((wrow*128 + whalf*64 + i*16) ^ ((wrow & 7) << 4))) = o;
      }
      #pragma unroll
      for (int i = 0; i < 4; ++i){
        const int chunk = wid * 4 + i;
        GLOAD16(Wt + (long)(chunk*8 + sub)*KD + k0 + kc8, sB[buf] + chunk*1024);
      }
    } else {
      #pragma unroll
      for (int i = 0; i < 4; ++i){
        const int chunk = wid * 4 + i;
        GLOAD16(Ab + (long)(chunk*8 + sub)*KD + k0 + kc8, sA[buf] + chunk*1024);
        GLOAD16(Wt + (long)(chunk*8 + sub)*KD + k0 + kc8, sB[buf] + chunk*1024);
      }
    }
  };

  constexpr int NT = KD / 64;
  STAGE(0, 0);
  __syncthreads();
  int cur = 0;
  for (int ks = 0; ks < NT; ++ks){
    if (ks + 1 < NT) STAGE(cur ^ 1, ks + 1);
    const char* pA = sA[cur]; const char* pB = sB[cur];
    #pragma unroll
    for (int kk = 0; kk < 2; ++kk){
      bf16x8 af[4], bf[4];
      #pragma unroll
      for (int mi = 0; mi < 4; ++mi){
        int m = wm*64 + mi*16 + (lane & 15);
        af[mi] = *reinterpret_cast<const bf16x8*>(
            pA + ((m*128 + kk*64 + (lane>>4)*16) ^ ((m & 7) << 4)));
      }
      #pragma unroll
      for (int ni = 0; ni < 4; ++ni){
        int c = wn*64 + ni*16 + (lane & 15);
        bf[ni] = *reinterpret_cast<const bf16x8*>(
            pB + ((c*128 + kk*64 + (lane>>4)*16) ^ ((c & 7) << 4)));
      }
      #pragma unroll
      for (int mi = 0; mi < 4; ++mi)
        #pragma unroll
        for (int ni = 0; ni < 4; ++ni)
          acc[mi][ni] = __builtin_amdgcn_mfma_f32_16x16x32_bf16(
              af[mi], bf[ni], acc[mi][ni], 0, 0, 0);
    }
    __syncthreads();
    cur ^= 1;
  }

  int chI[4]; float bv[4];
  #pragma unroll
  for (int ni = 0; ni < 4; ++ni){
    int ch = chT*128 + wn*64 + ni*16 + (lane & 15);
    chI[ni] = ch;
    bv[ni] = bias[ch];
  }
  if (MODE <= 1){
    float s[4] = {0,0,0,0}, sq[4] = {0,0,0,0};
    u16* outb = outH + (long)b * oBatch;
    #pragma unroll
    for (int mi = 0; mi < 4; ++mi){
      #pragma unroll
      for (int j = 0; j < 4; ++j){
        const long row = rowT*128 + wm*64 + mi*16 + (lane>>4)*4 + j;
        #pragma unroll
        for (int ni = 0; ni < 4; ++ni){
          float v = acc[mi][ni][j] + bv[ni];
          outb[row * NCH + chI[ni]] = f2b(v);
          if (MODE == 1){ s[ni] += v; sq[ni] += v * v; }
        }
      }
    }
    if (MODE == 1){
      #pragma unroll
      for (int ni = 0; ni < 4; ++ni){
        s[ni]  += __shfl_xor(s[ni], 16);  s[ni]  += __shfl_xor(s[ni], 32);
        sq[ni] += __shfl_xor(sq[ni], 16); sq[ni] += __shfl_xor(sq[ni], 32);
      }
      if (lane < 16){
        #pragma unroll
        for (int ni = 0; ni < 4; ++ni){
          atomicAdd(&statSum[chI[ni]], s[ni]);
          atomicAdd(&statSq[chI[ni]],  sq[ni]);
        }
      }
    }
  } else {
    const u16* rb = residT + (long)b * ((long)NRQ * 256);
    #pragma unroll
    for (int mi = 0; mi < 4; ++mi){
      const int nr0 = rowT*128 + wm*64 + mi*16 + (lane>>4)*4;
      #pragma unroll
      for (int ni = 0; ni < 4; ++ni){
        float4 o;
        o.x = fmaxf(acc[mi][ni][0] + bv[ni] + b2f(rb[(long)(nr0+0)*256 + chI[ni]]), 0.f);
        o.y = fmaxf(acc[mi][ni][1] + bv[ni] + b2f(rb[(long)(nr0+1)*256 + chI[ni]]), 0.f);
        o.z = fmaxf(acc[mi][ni][2] + bv[ni] + b2f(rb[(long)(nr0+2)*256 + chI[ni]]), 0.f);
        o.w = fmaxf(acc[mi][ni][3] + bv[ni] + b2f(rb[(long)(nr0+3)*256 + chI[ni]]), 0.f);
        *reinterpret_cast<float4*>(outF + (long)b*fBatch + (long)chI[ni]*NRQ + nr0) = o;
      }
    }
  }
}

// ---------------------------------------------------------------------------
// Fused kv-projection + attention, v4 (conflict-fixed).
// Block = 512 thr (8 waves), 64 feat rows (4 points) x 512 kv-channels.
// A staged in-kernel from fp32 feats (4-way-swizzled b16 writes, 2-way reads);
// W double-buffered via global_load_lds, BK=32.
// k -> sK [64 r][528B] XOR-swizzled; v -> sV [64 r][520B] row-major
// (conflict-free u16x2 PV reads). P fp32, head-pitch 272B. LDS 72KB.
// ---------------------------------------------------------------------------
__global__ __launch_bounds__(512, 4) void kvattn_k(
    const float* __restrict__ feats, const u16* __restrict__ wKV,
    const float* __restrict__ bKV, const u16* __restrict__ qT,
    const u16* __restrict__ qrT, u16* __restrict__ aggT)
{
  __shared__ __align__(16) char LDS[73728];
  char*  sAg = LDS;                     // GEMM A: 2 x 4KB [64 r][4 slot swz]
  char*  sW  = LDS + 8192;              // GEMM W: 2 x 32KB [512 ch][4 slot swz]
  char*  sK  = LDS;                     // attn K: [64 r][528B] swz ^((r&7)<<4)
  char*  sV  = LDS + 33792;             // attn V: [64 r][520B] plain
  float* sSf = (float*)(LDS + 67072);   // P fp32: [16 ph pitch68dw][16 kk][4 r]

  const int t = threadIdx.x, lane = t & 63, wid = t >> 6;
  const int wr = wid >> 2, wc = wid & 3;       // 2 x 4 waves for GEMM
  const int b = blockIdx.y;
  const long row0 = (long)blockIdx.x * 64;

  // A staging map: thread -> (k-elem chL, row quad nq)
  const int chL = t >> 4, nq = t & 15;
  const float* fbase = feats + (long)b * 256 * NKF + row0 + nq * 4;

  auto STAGEW = [&](int buf, int ks){
    const int k0 = ks * 32;
    #pragma unroll
    for (int i = 0; i < 4; ++i){
      const int cw = wid * 4 + i;
      const int ch = cw * 16 + (lane >> 2), jd = lane & 3;
      GLOAD16(wKV + (long)ch * 256 + k0 + ((jd ^ ((ch >> 1) & 3)) * 8),
              sW + buf * 32768 + cw * 1024);
    }
  };
  auto WRITEA = [&](int buf, float4 f){
    #pragma unroll
    for (int i = 0; i < 4; ++i){
      const int r = nq * 4 + i;
      const int byte = buf*4096 + r*64
                     + (((chL>>3) ^ ((r>>2)&3)) << 4) + (chL & 7)*2;
      float e = (i == 0) ? f.x : (i == 1) ? f.y : (i == 2) ? f.z : f.w;
      *reinterpret_cast<u16*>(sAg + byte) = f2b(e);
    }
  };

  f32x4 acc[2][8];
  #pragma unroll
  for (int i = 0; i < 2; ++i)
    #pragma unroll
    for (int j = 0; j < 8; ++j) acc[i][j] = (f32x4){0.f,0.f,0.f,0.f};

  {
    float4 a0 = *reinterpret_cast<const float4*>(fbase + (long)chL * NKF);
    STAGEW(0, 0);
    WRITEA(0, a0);
  }
  __syncthreads();
  int cur = 0;
  for (int ks = 0; ks < 8; ++ks){
    float4 an;
    if (ks < 7){
      an = *reinterpret_cast<const float4*>(fbase + (long)((ks+1)*32 + chL) * NKF);
      STAGEW(cur ^ 1, ks + 1);
    }
    const char* pA = sAg + cur * 4096;
    const char* pW = sW  + cur * 32768;
    bf16x8 af[2];
    #pragma unroll
    for (int mi = 0; mi < 2; ++mi){
      const int m = wr*32 + mi*16 + (lane & 15);
      af[mi] = *reinterpret_cast<const bf16x8*>(
          pA + m*64 + (((lane>>4) ^ ((m>>2)&3)) * 16));
    }
    #pragma unroll
    for (int ni = 0; ni < 8; ++ni){
      const int ch = wc*128 + ni*16 + (lane & 15);
      bf16x8 bf = *reinterpret_cast<const bf16x8*>(
          pW + ch*64 + (((lane>>4) ^ ((ch>>1)&3)) * 16));
      acc[0][ni] = __builtin_amdgcn_mfma_f32_16x16x32_bf16(af[0], bf, acc[0][ni], 0,0,0);
      acc[1][ni] = __builtin_amdgcn_mfma_f32_16x16x32_bf16(af[1], bf, acc[1][ni], 0,0,0);
    }
    if (ks < 7) WRITEA(cur ^ 1, an);
    __syncthreads();
    cur ^= 1;
  }

  // ---- C (+bias) -> sK (ch 0-255, swz) / sV (ch 256-511, row-major)
  {
    float bv[8];
    #pragma unroll
    for (int ni = 0; ni < 8; ++ni) bv[ni] = bKV[wc*128 + ni*16 + (lane & 15)];
    if (wc < 2){
      #pragma unroll
      for (int mi = 0; mi < 2; ++mi){
        const int p2 = wr*2 + mi;
        #pragma unroll
        for (int ni = 0; ni < 8; ++ni){
          const int ch = wc*128 + ni*16 + (lane & 15);
          #pragma unroll
          for (int j = 0; j < 4; ++j){
            const int kk2 = (lane>>4)*4 + j;
            *reinterpret_cast<u16*>(
                sK + (p2*16 + kk2)*528 + ((ch*2) ^ ((kk2 & 7) << 4))) =
                f2b(acc[mi][ni][j] + bv[ni]);
          }
        }
      }
    } else {
      #pragma unroll
      for (int mi = 0; mi < 2; ++mi){
        const int p2 = wr*2 + mi;
        #pragma unroll
        for (int ni = 0; ni < 8; ++ni){
          const int cv = (wc-2)*128 + ni*16 + (lane & 15);
          #pragma unroll
          for (int j = 0; j < 4; ++j){
            const int kk2 = (lane>>4)*4 + j;
            *reinterpret_cast<u16*>(sV + (p2*16 + kk2)*520 + cv*2) =
                f2b(acc[mi][ni][j] + bv[ni]);
          }
        }
      }
    }
  }
  __syncthreads();

  // ---- attention: wave = (rh, p); phase A lane = (h, kk)
  const int p = wid & 3, rh = wid >> 2;
  const int nqg = blockIdx.x * 4 + p;
  {
    const int h = lane >> 4, kk = lane & 15;
    const u16* qb = qT + ((long)b*NRQ + (long)nqg*4 + rh*2)*256 + h*64;
    const char* kr = sK + (p*16 + kk)*528;
    float l0 = 0.f, l1 = 0.f;
#if HAVE_DOT2
    #pragma unroll
    for (int d8 = 0; d8 < 8; ++d8){
      bpack K8, Q0, Q1;
      K8.v = *reinterpret_cast<const bf16x8*>(
          kr + ((h*128 + d8*16) ^ ((kk & 7) << 4)));
      Q0.v = *reinterpret_cast<const bf16x8*>(qb + d8*8);
      Q1.v = *reinterpret_cast<const bf16x8*>(qb + 256 + d8*8);
      #pragma unroll
      for (int pi = 0; pi < 4; ++pi){
        l0 = dot2(K8.p[pi], Q0.p[pi], l0);
        l1 = dot2(K8.p[pi], Q1.p[pi], l1);
      }
    }
#else
    #pragma unroll
    for (int d8 = 0; d8 < 8; ++d8){
      vpack K8, Q0, Q1;
      K8.v = *reinterpret_cast<const bf16x8*>(
          kr + ((h*128 + d8*16) ^ ((kk & 7) << 4)));
      Q0.v = *reinterpret_cast<const bf16x8*>(qb + d8*8);
      Q1.v = *reinterpret_cast<const bf16x8*>(qb + 256 + d8*8);
      #pragma unroll
      for (int e = 0; e < 8; ++e){
        float kf = b2f(K8.e[e]);
        l0 = fmaf(kf, b2f(Q0.e[e]), l0);
        l1 = fmaf(kf, b2f(Q1.e[e]), l1);
      }
    }
#endif
    float pr[2]; float lv[2] = {l0, l1};
    #pragma unroll
    for (int r = 0; r < 2; ++r){
      float x = lv[r] * 0.125f;
      float m = x;
      #pragma unroll
      for (int off = 1; off < 16; off <<= 1) m = fmaxf(m, __shfl_xor(m, off));
      float e = __expf(x - m);
      float ssum = e;
      #pragma unroll
      for (int off = 1; off < 16; off <<= 1) ssum += __shfl_xor(ssum, off);
      pr[r] = e / ssum;
    }
    *reinterpret_cast<float2*>(sSf + (p*4 + h)*68 + kk*4 + rh*2) =
        make_float2(pr[0], pr[1]);
  }
  __syncthreads();

  // ---- phase B: agg = v @ soft^T + qrT residual. lane -> 2 channels
  {
    const int c0 = rh*128 + lane*2;
    const int h = c0 >> 6;
    const char* vrow = sV + (p*16)*520;
    const float* ss = sSf + (p*4 + h)*68;
    float a[4][2] = {};
    #pragma unroll
    for (int kk = 0; kk < 16; ++kk){
      u16x2 vv = *reinterpret_cast<const u16x2*>(vrow + kk*520 + c0*2);
      float4 sv = *reinterpret_cast<const float4*>(ss + kk*4);
      float v0 = b2f(vv[0]), v1 = b2f(vv[1]);
      a[0][0] += sv.x*v0; a[0][1] += sv.x*v1;
      a[1][0] += sv.y*v0; a[1][1] += sv.y*v1;
      a[2][0] += sv.z*v0; a[2][1] += sv.z*v1;
      a[3][0] += sv.w*v0; a[3][1] += sv.w*v1;
    }
    const u16* rq = qrT + ((long)b*NRQ + (long)nqg*4)*256 + c0;
    u16* ob = aggT + ((long)b*NRQ + (long)nqg*4)*256 + c0;
    #pragma unroll
    for (int r = 0; r < 4; ++r){
      u16x2 q2 = *reinterpret_cast<const u16x2*>(rq + r*256);
      u16x2 pk;
      pk[0] = f2b(a[r][0] + b2f(q2[0]));
      pk[1] = f2b(a[r][1] + b2f(q2[1]));
      *reinterpret_cast<u16x2*>(ob + r*256) = pk;
    }
  }
}

__global__ void finalize_k(const float* __restrict__ st,
                           const float* __restrict__ gamma,
                           const float* __restrict__ beta,
                           float* __restrict__ out)   // scale[512], shift[512]
{
  int o = blockIdx.x*256 + threadIdx.x;
  const float inv = 1.f / 131072.f;                   // B*N*R
  float mean = st[o] * inv;
  float var  = st[512 + o] * inv - mean*mean;
  float sc   = gamma[o] * rsqrtf(var + 1e-5f);
  out[o]       = sc;
  out[512 + o] = beta[o] - mean * sc;
}

// ---------------------------------------------------------------------------
extern "C" void kernel_launch(void* const* d_in, const int* in_sizes, int n_in,
                              void* d_out, int out_size, void* d_ws, size_t ws_size,
                              hipStream_t stream)
{
  (void)in_sizes; (void)n_in; (void)out_size; (void)ws_size;
  const float* queries = (const float*)d_in[0];
  const float* feats   = (const float*)d_in[1];
  const float* Wq = (const float*)d_in[2];
  const float* bq = (const float*)d_in[3];
  const float* Wk = (const float*)d_in[4];
  const float* bk = (const float*)d_in[5];
  const float* Wv = (const float*)d_in[6];
  const float* bv = (const float*)d_in[7];
  const float* W1 = (const float*)d_in[8];
  const float* b1 = (const float*)d_in[9];
  const float* gamma = (const float*)d_in[10];
  const float* beta  = (const float*)d_in[11];
  const float* W2 = (const float*)d_in[12];
  const float* b2 = (const float*)d_in[13];

  // ws layout (bytes):
  //   [0, 134.2M)        : h1T bf16 [B][NRQ][512]
  //   [134.2M, 201.3M)   : qrT bf16 [B][NRQ][256]
  //   [201.3M, 268.4M)   : qT bf16
  //   [268.4M, 335.5M)   : aggT bf16
  //   [335.5M, +8K)      : stats; then wT weights + bKV
  char* ws = (char*)d_ws;
  u16*   h1T   = (u16*)ws;
  u16*   qrT   = (u16*)(ws + 134217728L);
  u16*   qT    = (u16*)(ws + 201326592L);
  u16*   aggT  = (u16*)(ws + 268435456L);
  float* stats = (float*)(ws + 335544320L);
  float* scale = stats + 1024;
  float* shift = stats + 1536;
  u16*   wT    = (u16*)(ws + 335552512L);
  u16*   wKV   = wT;                 // 512 x 256
  u16*   wQ    = wT + 131072;        // 256 x 256
  u16*   wW1   = wT + 196608;        // 512 x 256
  u16*   wW2   = wT + 327680;        // 256 x 512
  float* bKV   = (float*)(wT + 458752);

  cvtW_k<<<dim3(224), 256, 0, stream>>>(Wk, Wv, Wq, W1, W2, wT);
  prep_k<<<dim3(6), 256, 0, stream>>>(bk, bv, bKV, stats);

  // queries -> qrT bf16 [B][NRQ][256]
  transpose_k<<<dim3(NRQ/64, NB), 256, 0, stream>>>(queries, qrT, NRQ, (long)NRQ*256);

  // qT = qrT @ Wq^T + bq
  gemm_k<0, 256><<<dim3(512, 1, NB), 256, 0, stream>>>(
      qrT, (long)NRQ*256, 2, wQ, bq,
      qT, (long)NRQ*256, 256, nullptr, nullptr, nullptr, nullptr,
      nullptr, nullptr, 0);

  // fused kv-proj + attention (reads fp32 feats directly) -> aggT
  kvattn_k<<<dim3(NKF/64, NB), 512, 0, stream>>>(feats, wKV, bKV, qT, qrT, aggT);

  // h1 = aggT @ W1^T + b1 -> bf16 + BN stats
  gemm_k<1, 256><<<dim3(1024, 1, NB), 256, 0, stream>>>(
      aggT, (long)NRQ*256, 4, wW1, b1,
      h1T, (long)NRQ*512, 512, stats, stats + 512, nullptr, nullptr,
      nullptr, nullptr, 0);

  finalize_k<<<dim3(2), 256, 0, stream>>>(stats, gamma, beta, scale);

  // d_out = relu( relu(bn(h1)) @ W2^T + b2 + aggT ) -> fp32 [B][256][NRQ]
  // BN+ReLU fused into the A-staging path (MODE 3)
  gemm_k<3, 512><<<dim3(512, 1, NB), 256, 0, stream>>>(
      h1T, (long)NRQ*512, 2, wW2, b2,
      nullptr, 0, 256, nullptr, nullptr, scale, shift,
      aggT, (float*)d_out, (long)256*NRQ);
}